// Round 7
// baseline (450.554 us; speedup 1.0000x reference)
//
#include <hip/hip_runtime.h>
#include <math.h>

#define H 128
#define STC 152   // LDS stride (shorts) for bf16 A-tiles
#define SOT 136   // LDS stride (shorts) for staged bf16 output tiles
#define SPQ 136   // LDS stride (shorts) for bf16 Spq
#define Z2S 69    // LDS stride (floats) for z2

typedef __attribute__((ext_vector_type(8))) short short8;
typedef __attribute__((ext_vector_type(4))) float f32x4;

__device__ inline float bflo(unsigned int v) { return __uint_as_float(v << 16); }
__device__ inline float bfhi(unsigned int v) { return __uint_as_float(v & 0xffff0000u); }
__device__ inline float bf2f(unsigned short v) { return __uint_as_float(((unsigned int)v) << 16); }

// single-instruction bf16 pair pack (RNE)
__device__ inline unsigned int cvtpk(float lo, float hi) {
    unsigned int r;
    asm("v_cvt_pk_bf16_f32 %0, %1, %2" : "=v"(r) : "v"(lo), "v"(hi));
    return r;
}
__device__ inline unsigned short f2bf1(float f) {
    unsigned int r;
    asm("v_cvt_pk_bf16_f32 %0, %1, %1" : "=v"(r) : "v"(f));
    return (unsigned short)r;
}

// column-interleave permutation: storage col for logical col L.
__device__ inline int permcol(int T, int lm) {   // T = logical tile (0..7)
    return 32 * (T >> 1) + 2 * lm + (T & 1);
}
// inverse: logical row for storage row k (for Wc2 K-dim pack)
__device__ inline int kperm(int k) {
    int u = k >> 1;
    return 32 * (u >> 4) + (u & 15) + ((k & 1) << 4);
}

// ---------------- graph build ----------------

__global__ void count_kernel(const int* __restrict__ col, int E, int* __restrict__ cnt) {
    int e = blockIdx.x * blockDim.x + threadIdx.x;
    if (e < E) atomicAdd(&cnt[col[e]], 1);
}

__global__ void scan_sum_kernel(const int* __restrict__ cnt, int N, int* __restrict__ bsum) {
    int b = blockIdx.x, t = threadIdx.x;
    int base = b * 1024 + t * 4;
    int s = 0;
#pragma unroll
    for (int g = 0; g < 4; ++g) {
        int i = base + g;
        if (i < N) s += cnt[i];
    }
    for (int off = 32; off >= 1; off >>= 1) s += __shfl_down(s, off, 64);
    __shared__ int ws[4];
    if ((t & 63) == 0) ws[t >> 6] = s;
    __syncthreads();
    if (t == 0) bsum[b] = ws[0] + ws[1] + ws[2] + ws[3];
}

__global__ void scan_offsets_kernel(const int* __restrict__ bsum, int nb,
                                    int* __restrict__ boff, int* __restrict__ col_start, int N) {
    int lane = threadIdx.x;
    int v = (lane < nb) ? bsum[lane] : 0;
    int incl = v;
    for (int off = 1; off < 64; off <<= 1) {
        int u = __shfl_up(incl, off, 64);
        if (lane >= off) incl += u;
    }
    if (lane < nb) boff[lane] = incl - v;
    if (lane == 63) col_start[N] = incl;
}

// also emits xs = dinv-prescaled x rows (folds dinv into the layer-1 gather source)
__global__ void scan_write_kernel(const int* __restrict__ cnt, int N, const int* __restrict__ boff,
                                  int* __restrict__ col_start, int* __restrict__ cursor,
                                  float* __restrict__ dinv,
                                  const float* __restrict__ x, float* __restrict__ xs) {
    int b = blockIdx.x, t = threadIdx.x;
    int lane = t & 63, wv = t >> 6;
    int base = b * 1024 + t * 4;
    int c[4];
    int s = 0;
#pragma unroll
    for (int g = 0; g < 4; ++g) {
        int i = base + g;
        c[g] = (i < N) ? cnt[i] : 0;
        s += c[g];
    }
    int incl = s;
    for (int off = 1; off < 64; off <<= 1) {
        int u = __shfl_up(incl, off, 64);
        if (lane >= off) incl += u;
    }
    __shared__ int ws[4];
    if (lane == 63) ws[wv] = incl;
    __syncthreads();
    int run = boff[b] + incl - s;
    for (int w = 0; w < wv; ++w) run += ws[w];
#pragma unroll
    for (int g = 0; g < 4; ++g) {
        int i = base + g;
        if (i < N) {
            col_start[i] = run;
            cursor[i] = run;
            float di = rsqrtf((float)(c[g] + 1));
            dinv[i] = di;
            float4 xa = ((const float4*)x)[i * 2];
            float4 xb = ((const float4*)x)[i * 2 + 1];
            xa.x *= di; xa.y *= di; xa.z *= di; xa.w *= di;
            xb.x *= di; xb.y *= di; xb.z *= di; xb.w *= di;
            ((float4*)xs)[i * 2] = xa;
            ((float4*)xs)[i * 2 + 1] = xb;
            run += c[g];
        }
    }
}

__global__ void scatter_kernel(const int* __restrict__ row, const int* __restrict__ col, int E,
                               int* __restrict__ cursor, int* __restrict__ csc_src,
                               int2* __restrict__ csc_ec) {
    int e = blockIdx.x * blockDim.x + threadIdx.x;
    if (e < E) {
        int c = col[e];
        int p = atomicAdd(&cursor[c], 1);
        csc_src[p] = row[e];
        csc_ec[p] = make_int2(e, c);
    }
}

// ---------------- GCN: aggregate-then-transform (bf16 dinv-prescaled features) ----------------

// wave-per-node aggregation on prescaled xs: 1 gather per neighbor (no dinv gather)
__global__ __launch_bounds__(256) void aggx_kernel(
    const float* __restrict__ xs, const int* __restrict__ col_start,
    const int* __restrict__ csc_src, const float* __restrict__ dinv,
    float* __restrict__ aggx, int N) {
    int wv = threadIdx.x >> 6, lane = threadIdx.x & 63;
    int i = blockIdx.x * 4 + wv;
    if (i >= N) return;
    int f = lane & 7, j = lane >> 3;
    int s0 = col_start[i], s1 = col_start[i + 1];
    float acc = 0.f;
    int p = s0 + j;
    for (; p + 8 < s1; p += 16) {
        int sa = csc_src[p], sb = csc_src[p + 8];
        acc += xs[sa * 8 + f] + xs[sb * 8 + f];
    }
    if (p < s1)
        acc += xs[csc_src[p] * 8 + f];
    acc += __shfl_xor(acc, 8, 64);
    acc += __shfl_xor(acc, 16, 64);
    acc += __shfl_xor(acc, 32, 64);
    if (j == 0) {
        float di = dinv[i];
        aggx[i * 8 + f] = di * (acc + xs[i * 8 + f]);
    }
}

__global__ void xform8bf_kernel(const float* __restrict__ aggx, const float* __restrict__ W,
                                const float* __restrict__ b, const float* __restrict__ dinv,
                                unsigned int* __restrict__ out, int N) {
    int t = blockIdx.x * 256 + threadIdx.x;
    int i = t >> 6, jp = t & 63;
    if (i >= N) return;
    const float* ar = aggx + i * 8;
    float sc = dinv[i];
    int j0 = jp * 2;
    float a0 = b[j0], a1 = b[j0 + 1];
#pragma unroll
    for (int k = 0; k < 8; ++k) {
        float av = ar[k];
        a0 = fmaf(av, W[k * 128 + j0], a0);
        a1 = fmaf(av, W[k * 128 + j0 + 1], a1);
    }
    out[(size_t)i * 64 + jp] = cvtpk(sc * fmaxf(a0, 0.f), sc * fmaxf(a1, 0.f));
}

// wave-per-node row-sum of prescaled bf16 rows; index loads software-pipelined
// (batch n+1's csc_src load issued between batch n's gathers and their consumption)
__global__ __launch_bounds__(256) void agg128bf_kernel(
    const unsigned int* __restrict__ hd, const int* __restrict__ col_start,
    const int* __restrict__ csc_src, const float* __restrict__ dinv,
    unsigned int* __restrict__ out, int N) {
    int wv = threadIdx.x >> 6, lane = threadIdx.x & 63;
    int i = blockIdx.x * 4 + wv;
    if (i >= N) return;
    int s0 = col_start[i], s1 = col_start[i + 1];
    float ax = 0.f, ay = 0.f;
    int p = s0;
    if (p + 16 <= s1) {
        int idx[16];
#pragma unroll
        for (int k = 0; k < 16; ++k) idx[k] = csc_src[p + k];
        for (; p + 32 <= s1; p += 16) {
            unsigned int v[16];
#pragma unroll
            for (int k = 0; k < 16; ++k)
                v[k] = hd[(size_t)idx[k] * 64 + lane];
            int idn[16];
#pragma unroll
            for (int k = 0; k < 16; ++k) idn[k] = csc_src[p + 16 + k];
#pragma unroll
            for (int k = 0; k < 16; ++k) { ax += bflo(v[k]); ay += bfhi(v[k]); }
#pragma unroll
            for (int k = 0; k < 16; ++k) idx[k] = idn[k];
        }
        {
            unsigned int v[16];
#pragma unroll
            for (int k = 0; k < 16; ++k)
                v[k] = hd[(size_t)idx[k] * 64 + lane];
#pragma unroll
            for (int k = 0; k < 16; ++k) { ax += bflo(v[k]); ay += bfhi(v[k]); }
        }
        p += 16;
    }
    for (; p + 4 <= s1; p += 4) {
        unsigned int v0 = hd[(size_t)csc_src[p + 0] * 64 + lane];
        unsigned int v1 = hd[(size_t)csc_src[p + 1] * 64 + lane];
        unsigned int v2 = hd[(size_t)csc_src[p + 2] * 64 + lane];
        unsigned int v3 = hd[(size_t)csc_src[p + 3] * 64 + lane];
        ax += bflo(v0) + bflo(v1) + bflo(v2) + bflo(v3);
        ay += bfhi(v0) + bfhi(v1) + bfhi(v2) + bfhi(v3);
    }
    for (; p < s1; ++p) {
        unsigned int v = hd[(size_t)csc_src[p] * 64 + lane];
        ax += bflo(v); ay += bfhi(v);
    }
    float di = dinv[i];
    unsigned int vs = hd[(size_t)i * 64 + lane];
    float rx = di * (ax + bflo(vs));
    float ry = di * (ay + bfhi(vs));
    out[(size_t)i * 64 + lane] = cvtpk(rx, ry);
}

__global__ __launch_bounds__(256) void xform_mfma_kernel(
    const unsigned short* __restrict__ in, const unsigned short* __restrict__ Bp,
    const float* __restrict__ b, const float* __restrict__ scale,
    unsigned short* __restrict__ out, int N) {
    __shared__ __align__(16) unsigned short sm[64 * STC];
    int tid = threadIdx.x;
    int i0 = blockIdx.x * 64;
    for (int u = tid; u < 1024; u += 256) {
        int i = u >> 4, l = u & 15;
        int node = i0 + i; if (node >= N) node = N - 1;
        uint4 v = ((const uint4*)in)[(size_t)node * 16 + l];
        *(uint4*)&sm[i * STC + l * 8] = v;
    }
    __syncthreads();
    int lane = tid & 63, w = tid >> 6, lm = lane & 15, quad = lane >> 4;
    int nt0 = 2 * w, nt1 = 2 * w + 1;
    f32x4 acc0[4], acc1[4];
    {
        float bv0 = b[nt0 * 16 + lm], bv1 = b[nt1 * 16 + lm];
        for (int m = 0; m < 4; ++m)
            for (int r = 0; r < 4; ++r) { acc0[m][r] = bv0; acc1[m][r] = bv1; }
    }
#pragma unroll
    for (int s = 0; s < 4; ++s) {
        short8 b0 = *(const short8*)&Bp[((size_t)(s * 8 + nt0) * 64 + lane) * 8];
        short8 b1 = *(const short8*)&Bp[((size_t)(s * 8 + nt1) * 64 + lane) * 8];
#pragma unroll
        for (int m = 0; m < 4; ++m) {
            short8 afr = *(const short8*)&sm[(m * 16 + lm) * STC + s * 32 + quad * 8];
            acc0[m] = __builtin_amdgcn_mfma_f32_16x16x32_bf16(afr, b0, acc0[m], 0, 0, 0);
            acc1[m] = __builtin_amdgcn_mfma_f32_16x16x32_bf16(afr, b1, acc1[m], 0, 0, 0);
        }
    }
    __syncthreads();
    for (int m = 0; m < 4; ++m)
        for (int r = 0; r < 4; ++r) {
            int rw = m * 16 + quad * 4 + r;
            int node = i0 + rw; if (node >= N) node = N - 1;
            float sc = scale ? scale[node] : 1.f;
            sm[rw * SOT + nt0 * 16 + lm] = f2bf1(sc * fmaxf(acc0[m][r], 0.f));
            sm[rw * SOT + nt1 * 16 + lm] = f2bf1(sc * fmaxf(acc1[m][r], 0.f));
        }
    __syncthreads();
    for (int u = tid; u < 1024; u += 256) {
        int i = u >> 4, l = u & 15;
        int node = i0 + i;
        if (node < N)
            *(uint4*)&out[(size_t)node * 128 + l * 8] = *(uint4*)&sm[i * SOT + l * 8];
    }
}

// ---------------- classifier weight prep ----------------

__global__ void weff_kernel(const float* __restrict__ We2, const float* __restrict__ Wc1,
                            float* __restrict__ Weff) {
    int idx = blockIdx.x * blockDim.x + threadIdx.x;
    int k = idx >> 7, c = idx & 127;
    float acc = 0.f;
    for (int j = 0; j < 128; ++j)
        acc = fmaf(We2[k * 128 + j], Wc1[(256 + j) * 128 + c], acc);
    Weff[idx] = acc;
}

__global__ void bc1p_kernel(const float* __restrict__ bc1, const float* __restrict__ be2,
                            const float* __restrict__ Wc1, float* __restrict__ bc1p) {
    int c = threadIdx.x;
    float acc = bc1[c];
    for (int j = 0; j < 128; ++j)
        acc = fmaf(be2[j], Wc1[(256 + j) * 128 + c], acc);
    bc1p[c] = acc;
}

__global__ void packg_kernel(const float* __restrict__ src, unsigned short* __restrict__ dst) {
    int idx = blockIdx.x * 256 + threadIdx.x;  // 2048
    int s = idx >> 9, nt = (idx >> 6) & 7, lane = idx & 63;
    int quad = lane >> 4, lm = lane & 15;
    int n = nt * 16 + lm, k0 = s * 32 + quad * 8;
    unsigned int p[4];
#pragma unroll
    for (int g = 0; g < 4; ++g)
        p[g] = cvtpk(src[(k0 + 2 * g) * 128 + n], src[(k0 + 2 * g + 1) * 128 + n]);
    *(uint4*)&dst[(size_t)idx * 8] = make_uint4(p[0], p[1], p[2], p[3]);
}

// Wc2 pack with K-rows permuted to match interleaved z1 storage order
__global__ void pack2_kernel(const float* __restrict__ Wc2, unsigned short* __restrict__ Bp2) {
    int idx = blockIdx.x * 256 + threadIdx.x;  // 1024
    int s = idx >> 8, nt = (idx >> 6) & 3, lane = idx & 63;
    int quad = lane >> 4, lm = lane & 15;
    int n = nt * 16 + lm, k0 = s * 32 + quad * 8;
    unsigned int p[4];
#pragma unroll
    for (int g = 0; g < 4; ++g)
        p[g] = cvtpk(Wc2[kperm(k0 + 2 * g) * 64 + n], Wc2[kperm(k0 + 2 * g + 1) * 64 + n]);
    *(uint4*)&Bp2[(size_t)idx * 8] = make_uint4(p[0], p[1], p[2], p[3]);
}

__global__ void packwe1_kernel(const float* __restrict__ We1, const float* __restrict__ be1,
                               unsigned short* __restrict__ BpE) {
    int idx = blockIdx.x * 256 + threadIdx.x;  // 512
    if (idx >= 512) return;
    int nt = idx >> 6, lane = idx & 63;
    int quad = lane >> 4, lm = lane & 15;
    int n = nt * 16 + lm, k0 = quad * 8;
    unsigned int p[4];
#pragma unroll
    for (int g = 0; g < 4; ++g) {
        int r0 = k0 + 2 * g, r1 = r0 + 1;
        float v0 = (r0 < 4) ? We1[r0 * 128 + n] : ((r0 == 4) ? be1[n] : 0.f);
        float v1 = (r1 < 4) ? We1[r1 * 128 + n] : ((r1 == 4) ? be1[n] : 0.f);
        p[g] = cvtpk(v0, v1);
    }
    *(uint4*)&BpE[(size_t)idx * 8] = make_uint4(p[0], p[1], p[2], p[3]);
}

// ---------------- fused h3 transform + P/Q precompute ----------------

__global__ __launch_bounds__(256) void h3pq_kernel(
    const unsigned short* __restrict__ in, const unsigned short* __restrict__ BpW3,
    const float* __restrict__ b3,
    const unsigned short* __restrict__ BpA, const unsigned short* __restrict__ BpB,
    const float* __restrict__ bc1p,
    unsigned short* __restrict__ P, unsigned short* __restrict__ Q, int N) {
    __shared__ __align__(16) unsigned short At[64 * STC];
    __shared__ __align__(16) unsigned short Hs[64 * SOT];
    int tid = threadIdx.x;
    int i0 = blockIdx.x * 64;
    for (int u = tid; u < 1024; u += 256) {
        int i = u >> 4, l = u & 15;
        int node = i0 + i; if (node >= N) node = N - 1;
        uint4 v = ((const uint4*)in)[(size_t)node * 16 + l];
        *(uint4*)&At[i * STC + l * 8] = v;
    }
    __syncthreads();
    int lane = tid & 63, w = tid >> 6, lm = lane & 15, quad = lane >> 4;

    {
        int nt0 = 2 * w, nt1 = 2 * w + 1;
        f32x4 a0[4], a1[4];
        float bv0 = b3[nt0 * 16 + lm], bv1 = b3[nt1 * 16 + lm];
        for (int m = 0; m < 4; ++m)
            for (int r = 0; r < 4; ++r) { a0[m][r] = bv0; a1[m][r] = bv1; }
#pragma unroll
        for (int s = 0; s < 4; ++s) {
            short8 b0 = *(const short8*)&BpW3[((size_t)(s * 8 + nt0) * 64 + lane) * 8];
            short8 b1 = *(const short8*)&BpW3[((size_t)(s * 8 + nt1) * 64 + lane) * 8];
#pragma unroll
            for (int m = 0; m < 4; ++m) {
                short8 afr = *(const short8*)&At[(m * 16 + lm) * STC + s * 32 + quad * 8];
                a0[m] = __builtin_amdgcn_mfma_f32_16x16x32_bf16(afr, b0, a0[m], 0, 0, 0);
                a1[m] = __builtin_amdgcn_mfma_f32_16x16x32_bf16(afr, b1, a1[m], 0, 0, 0);
            }
        }
        __syncthreads();
        for (int m = 0; m < 4; ++m)
            for (int r = 0; r < 4; ++r) {
                int rw = m * 16 + quad * 4 + r;
                Hs[rw * SOT + nt0 * 16 + lm] = f2bf1(fmaxf(a0[m][r], 0.f));
                Hs[rw * SOT + nt1 * 16 + lm] = f2bf1(fmaxf(a1[m][r], 0.f));
            }
    }
    __syncthreads();

    int half = w & 1;
    const unsigned short* Bp = (w >> 1) ? BpB : BpA;
    f32x4 acc[4][4];
    for (int nt = 0; nt < 4; ++nt) {
        float bv = (w >> 1) ? 0.f : bc1p[half * 64 + nt * 16 + lm];
        for (int m = 0; m < 4; ++m)
            for (int r = 0; r < 4; ++r) acc[nt][m][r] = bv;
    }
#pragma unroll
    for (int s = 0; s < 4; ++s) {
        short8 afr[4];
#pragma unroll
        for (int m = 0; m < 4; ++m)
            afr[m] = *(const short8*)&Hs[(m * 16 + lm) * SOT + s * 32 + quad * 8];
#pragma unroll
        for (int nt = 0; nt < 4; ++nt) {
            short8 bfr = *(const short8*)&Bp[((size_t)(s * 8 + half * 4 + nt) * 64 + lane) * 8];
#pragma unroll
            for (int m = 0; m < 4; ++m)
                acc[nt][m] = __builtin_amdgcn_mfma_f32_16x16x32_bf16(afr[m], bfr, acc[nt][m], 0, 0, 0);
        }
    }
    __syncthreads();
    unsigned short* St = At;

    // write P/Q with column-interleave permutation (consumed by classifier add-back)
    if (w < 2) {
        for (int nt = 0; nt < 4; ++nt) {
            int T = half * 4 + nt;
            int pc = permcol(T, lm);
            for (int m = 0; m < 4; ++m)
                for (int r = 0; r < 4; ++r) {
                    int rw = m * 16 + quad * 4 + r;
                    St[rw * SOT + pc] = f2bf1(acc[nt][m][r]);
                }
        }
    }
    __syncthreads();
    for (int u = tid; u < 1024; u += 256) {
        int i = u >> 4, l = u & 15;
        int node = i0 + i;
        if (node < N)
            *(uint4*)&P[(size_t)node * 128 + l * 8] = *(uint4*)&St[i * SOT + l * 8];
    }
    __syncthreads();
    if (w >= 2) {
        for (int nt = 0; nt < 4; ++nt) {
            int T = half * 4 + nt;
            int pc = permcol(T, lm);
            for (int m = 0; m < 4; ++m)
                for (int r = 0; r < 4; ++r) {
                    int rw = m * 16 + quad * 4 + r;
                    St[rw * SOT + pc] = f2bf1(acc[nt][m][r]);
                }
        }
    }
    __syncthreads();
    for (int u = tid; u < 1024; u += 256) {
        int i = u >> 4, l = u & 15;
        int node = i0 + i;
        if (node < N)
            *(uint4*)&Q[(size_t)node * 128 + l * 8] = *(uint4*)&St[i * SOT + l * 8];
    }
}

// ---------------- fused classifier, all-MFMA (1 tile/block; interleaved Spq/z1; post-MFMA add-back) ----------------

__global__ __launch_bounds__(256, 4) void classifier_mfma2(
    const int* __restrict__ csc_src, const int2* __restrict__ csc_ec,
    const float* __restrict__ ea, const unsigned short* __restrict__ BpE,
    const unsigned short* __restrict__ P, const unsigned short* __restrict__ Q,
    const unsigned short* __restrict__ BpU, const unsigned short* __restrict__ Bp2,
    const float* __restrict__ bc2, const float* __restrict__ Wc3, const float* __restrict__ bc3,
    float* __restrict__ out, int E) {
    __shared__ __align__(16) unsigned char smem[37888];
    unsigned short* SpqB = (unsigned short*)smem;         // [64][SPQ] bf16 (interleaved cols)
    float* z2 = (float*)smem;                             // [64][Z2S] fp32 (overlay)
    unsigned short* At = (unsigned short*)(smem + 17664); // [64][STC] bf16 (t, then z1)
    unsigned short* z1 = At;                              // overlay
    float* part = (float*)(smem + 17664);                 // [4][64] (overlay)
    int* sS = (int*)(smem + 37120);
    int* eS = sS + 64;
    int* cS = eS + 64;

    int tid = threadIdx.x;
    int lane = tid & 63, w = tid >> 6, lm = lane & 15, quad = lane >> 4;
    int e0 = blockIdx.x * 64;

    short8 bE0 = *(const short8*)&BpE[((size_t)(2 * w) * 64 + lane) * 8];
    short8 bE1 = *(const short8*)&BpE[((size_t)(2 * w + 1) * 64 + lane) * 8];
    short8 b0s[4], b1s[4], b2s[4];
#pragma unroll
    for (int s = 0; s < 4; ++s) {
        b0s[s] = *(const short8*)&BpU[((size_t)(s * 8 + 2 * w) * 64 + lane) * 8];
        b1s[s] = *(const short8*)&BpU[((size_t)(s * 8 + 2 * w + 1) * 64 + lane) * 8];
        b2s[s] = *(const short8*)&Bp2[((size_t)(s * 4 + w) * 64 + lane) * 8];
    }
    float bv2 = bc2[w * 16 + lm];

    if (tid < 64) {
        int p = e0 + tid; if (p >= E) p = E - 1;
        sS[tid] = csc_src[p];
        int2 ec = csc_ec[p];
        eS[tid] = ec.x; cS[tid] = ec.y;
    }
    __syncthreads();

    // ---- issue ALL first-phase gathers before any conversion work ----
    float4 av[4];
    if (quad == 0) {
#pragma unroll
        for (int m = 0; m < 4; ++m)
            av[m] = ((const float4*)ea)[eS[m * 16 + lm]];
    }

    {
        const uint4* P4 = (const uint4*)P;
        const uint4* Q4 = (const uint4*)Q;
        int l = tid & 15;
        uint4 pv[4], qv[4];
#pragma unroll
        for (int j = 0; j < 4; ++j) {
            int i = (tid >> 4) + 16 * j;
            pv[j] = P4[(size_t)sS[i] * 16 + l];
            qv[j] = Q4[(size_t)cS[i] * 16 + l];
        }
#pragma unroll
        for (int j = 0; j < 4; ++j) {
            int i = (tid >> 4) + 16 * j;
            uint4 o;
            o.x = cvtpk(bflo(pv[j].x) + bflo(qv[j].x), bfhi(pv[j].x) + bfhi(qv[j].x));
            o.y = cvtpk(bflo(pv[j].y) + bflo(qv[j].y), bfhi(pv[j].y) + bfhi(qv[j].y));
            o.z = cvtpk(bflo(pv[j].z) + bflo(qv[j].z), bfhi(pv[j].z) + bfhi(qv[j].z));
            o.w = cvtpk(bflo(pv[j].w) + bflo(qv[j].w), bfhi(pv[j].w) + bfhi(qv[j].w));
            *(uint4*)&SpqB[i * SPQ + l * 8] = o;
        }
    }

    short8 eaf[4];
#pragma unroll
    for (int m = 0; m < 4; ++m) eaf[m] = (short8){0, 0, 0, 0, 0, 0, 0, 0};
    if (quad == 0) {
#pragma unroll
        for (int m = 0; m < 4; ++m) {
            eaf[m][0] = (short)f2bf1(av[m].x);
            eaf[m][1] = (short)f2bf1(av[m].y);
            eaf[m][2] = (short)f2bf1(av[m].z);
            eaf[m][3] = (short)f2bf1(av[m].w);
            eaf[m][4] = (short)0x3F80;  // 1.0 bf16
        }
    }

    {
        f32x4 zacc = {0.f, 0.f, 0.f, 0.f};
#pragma unroll
        for (int m = 0; m < 4; ++m) {
            f32x4 t0 = __builtin_amdgcn_mfma_f32_16x16x32_bf16(eaf[m], bE0, zacc, 0, 0, 0);
            f32x4 t1 = __builtin_amdgcn_mfma_f32_16x16x32_bf16(eaf[m], bE1, zacc, 0, 0, 0);
#pragma unroll
            for (int r = 0; r < 4; ++r) {
                int rw = m * 16 + quad * 4 + r;
                At[rw * STC + 32 * w + lm]      = f2bf1(fmaxf(t0[r], 0.f));
                At[rw * STC + 32 * w + 16 + lm] = f2bf1(fmaxf(t1[r], 0.f));
            }
        }
    }
    __syncthreads();

    f32x4 acc0[4], acc1[4];
    for (int m = 0; m < 4; ++m)
        for (int r = 0; r < 4; ++r) { acc0[m][r] = 0.f; acc1[m][r] = 0.f; }
#pragma unroll
    for (int s = 0; s < 4; ++s) {
#pragma unroll
        for (int m = 0; m < 4; ++m) {
            short8 afr = *(const short8*)&At[(m * 16 + lm) * STC + s * 32 + quad * 8];
            acc0[m] = __builtin_amdgcn_mfma_f32_16x16x32_bf16(afr, b0s[s], acc0[m], 0, 0, 0);
            acc1[m] = __builtin_amdgcn_mfma_f32_16x16x32_bf16(afr, b1s[s], acc1[m], 0, 0, 0);
        }
    }
    // add-back: one uint per (m,r) holds both acc0 (lo) and acc1 (hi) columns
    {
        const unsigned int* Spq32 = (const unsigned int*)SpqB;
        for (int m = 0; m < 4; ++m)
            for (int r = 0; r < 4; ++r) {
                int rw = m * 16 + quad * 4 + r;
                unsigned int pq = Spq32[rw * (SPQ / 2) + 16 * w + lm];
                acc0[m][r] = fmaxf(acc0[m][r] + bflo(pq), 0.f);
                acc1[m][r] = fmaxf(acc1[m][r] + bfhi(pq), 0.f);
            }
    }
    __syncthreads();
    {
        unsigned int* z1u = (unsigned int*)z1;
        for (int m = 0; m < 4; ++m)
            for (int r = 0; r < 4; ++r) {
                int rw = m * 16 + quad * 4 + r;
                z1u[rw * (STC / 2) + 16 * w + lm] = cvtpk(acc0[m][r], acc1[m][r]);
            }
    }
    __syncthreads();

    {
        f32x4 acc2[4];
        for (int m = 0; m < 4; ++m)
            for (int r = 0; r < 4; ++r) acc2[m][r] = bv2;
#pragma unroll
        for (int s = 0; s < 4; ++s) {
#pragma unroll
            for (int m = 0; m < 4; ++m) {
                short8 afr = *(const short8*)&z1[(m * 16 + lm) * STC + s * 32 + quad * 8];
                acc2[m] = __builtin_amdgcn_mfma_f32_16x16x32_bf16(afr, b2s[s], acc2[m], 0, 0, 0);
            }
        }
        for (int m = 0; m < 4; ++m)
            for (int r = 0; r < 4; ++r)
                z2[(m * 16 + quad * 4 + r) * Z2S + w * 16 + lm] = fmaxf(acc2[m][r], 0.f);
    }
    __syncthreads();

    {
        int e = tid & 63, q = tid >> 6;
        int c = q & 1, hf = q >> 1;
        const float* zr = z2 + e * Z2S + hf * 32;
        const float* wc = Wc3 + hf * 64 + c;
        float acc = 0.f;
#pragma unroll 8
        for (int kk = 0; kk < 32; ++kk)
            acc = fmaf(zr[kk], wc[2 * kk], acc);
        part[q * 64 + e] = acc;
    }
    __syncthreads();
    if (tid < 64) {
        int p = e0 + tid;
        if (p < E) {
            float l0 = bc3[0] + part[tid] + part[128 + tid];
            float l1 = bc3[1] + part[64 + tid] + part[192 + tid];
            float m = fmaxf(l0, l1);
            float lse = m + logf(expf(l0 - m) + expf(l1 - m));
            ((float2*)out)[eS[tid]] = make_float2(l0 - lse, l1 - lse);
        }
    }
}

// ---------------- launch ----------------

extern "C" void kernel_launch(void* const* d_in, const int* in_sizes, int n_in,
                              void* d_out, int out_size, void* d_ws, size_t ws_size,
                              hipStream_t stream) {
    const float* x   = (const float*)d_in[0];
    const int*   ei  = (const int*)d_in[1];
    const float* ea  = (const float*)d_in[2];
    const float* W1  = (const float*)d_in[3];
    const float* b1  = (const float*)d_in[4];
    const float* W2  = (const float*)d_in[5];
    const float* b2  = (const float*)d_in[6];
    const float* W3  = (const float*)d_in[7];
    const float* b3  = (const float*)d_in[8];
    const float* We1 = (const float*)d_in[9];
    const float* be1 = (const float*)d_in[10];
    const float* We2 = (const float*)d_in[11];
    const float* be2 = (const float*)d_in[12];
    const float* Wc1 = (const float*)d_in[13];
    const float* bc1 = (const float*)d_in[14];
    const float* Wc2 = (const float*)d_in[15];
    const float* bc2 = (const float*)d_in[16];
    const float* Wc3 = (const float*)d_in[17];
    const float* bc3 = (const float*)d_in[18];
    float* out = (float*)d_out;

    int N = in_sizes[0] / 8;
    int E = in_sizes[1] / 2;
    const int* row = ei;
    const int* col = ei + E;
    int NB = (N + 1023) / 1024;
    int ntiles = (E + 63) / 64;

    char* w = (char*)d_ws;
    auto alloc = [&](size_t bytes) { void* p = (void*)w; w += (bytes + 255) & ~(size_t)255; return p; };
    int*   cnt       = (int*)alloc((size_t)N * 4);
    int*   col_start = (int*)alloc((size_t)(N + 1) * 4);
    int*   cursor    = (int*)alloc((size_t)N * 4);
    int*   csc_src   = (int*)alloc((size_t)E * 4);
    int2*  csc_ec    = (int2*)alloc((size_t)E * 8);
    float* dinv      = (float*)alloc((size_t)N * 4);
    int*   bsum      = (int*)alloc(64 * 4);
    int*   boff      = (int*)alloc(64 * 4);
    float* Weff      = (float*)alloc(128 * 128 * 4);
    float* bc1p      = (float*)alloc(128 * 4);
    unsigned short* BpA  = (unsigned short*)alloc(32768);
    unsigned short* BpB  = (unsigned short*)alloc(32768);
    unsigned short* BpU  = (unsigned short*)alloc(32768);
    unsigned short* BpW2 = (unsigned short*)alloc(32768);
    unsigned short* BpW3 = (unsigned short*)alloc(32768);
    unsigned short* Bp2  = (unsigned short*)alloc(16384);
    unsigned short* BpE  = (unsigned short*)alloc(8192);
    float* aggx = (float*)alloc((size_t)N * 8 * 4);
    float* xs   = (float*)alloc((size_t)N * 8 * 4);
    unsigned short* bufA = (unsigned short*)alloc((size_t)N * H * 2);
    unsigned short* bufB = (unsigned short*)alloc((size_t)N * H * 2);
    unsigned short* Pm   = (unsigned short*)alloc((size_t)N * H * 2);
    unsigned short* Qm   = (unsigned short*)alloc((size_t)N * H * 2);

    // graph build (CSC with eid+col); scan_write also emits dinv-prescaled xs
    hipMemsetAsync(cnt, 0, (size_t)N * 4, stream);
    count_kernel<<<(E + 255) / 256, 256, 0, stream>>>(col, E, cnt);
    scan_sum_kernel<<<NB, 256, 0, stream>>>(cnt, N, bsum);
    scan_offsets_kernel<<<1, 64, 0, stream>>>(bsum, NB, boff, col_start, N);
    scan_write_kernel<<<NB, 256, 0, stream>>>(cnt, N, boff, col_start, cursor, dinv, x, xs);
    scatter_kernel<<<(E + 255) / 256, 256, 0, stream>>>(row, col, E, cursor, csc_src, csc_ec);

    // weight prep
    weff_kernel<<<64, 256, 0, stream>>>(We2, Wc1, Weff);
    bc1p_kernel<<<1, 128, 0, stream>>>(bc1, be2, Wc1, bc1p);
    packg_kernel<<<8, 256, 0, stream>>>(Wc1, BpA);
    packg_kernel<<<8, 256, 0, stream>>>(Wc1 + 128 * 128, BpB);
    packg_kernel<<<8, 256, 0, stream>>>(Weff, BpU);
    packg_kernel<<<8, 256, 0, stream>>>(W2, BpW2);
    packg_kernel<<<8, 256, 0, stream>>>(W3, BpW3);
    pack2_kernel<<<4, 256, 0, stream>>>(Wc2, Bp2);
    packwe1_kernel<<<2, 256, 0, stream>>>(We1, be1, BpE);

    // GCN: aggregate-then-transform, dinv-prescaled bf16 features
    aggx_kernel<<<(N + 3) / 4, 256, 0, stream>>>(xs, col_start, csc_src, dinv, aggx, N);
    xform8bf_kernel<<<(N * 64 + 255) / 256, 256, 0, stream>>>(aggx, W1, b1, dinv,
                                                              (unsigned int*)bufA, N);   // h1d
    agg128bf_kernel<<<(N + 3) / 4, 256, 0, stream>>>((const unsigned int*)bufA, col_start, csc_src,
                                                     dinv, (unsigned int*)bufB, N);      // agg2
    xform_mfma_kernel<<<(N + 63) / 64, 256, 0, stream>>>(bufB, BpW2, b2, dinv, bufA, N); // h2d
    agg128bf_kernel<<<(N + 3) / 4, 256, 0, stream>>>((const unsigned int*)bufA, col_start, csc_src,
                                                     dinv, (unsigned int*)bufB, N);      // agg3
    h3pq_kernel<<<(N + 63) / 64, 256, 0, stream>>>(bufB, BpW3, b3, BpA, BpB, bc1p, Pm, Qm, N);

    // fused all-MFMA classifier in CSC order (1 tile/block)
    classifier_mfma2<<<ntiles, 256, 0, stream>>>(
        csc_src, csc_ec, ea, BpE, Pm, Qm, BpU, Bp2, bc2, Wc3, bc3, out, E);
}

// Round 8
// 438.107 us; speedup vs baseline: 1.0284x; 1.0284x over previous
//
#include <hip/hip_runtime.h>
#include <math.h>

#define H 128
#define STC 152   // LDS stride (shorts) for bf16 A-tiles
#define SOT 136   // LDS stride (shorts) for staged bf16 output tiles
#define SPQ 136   // LDS stride (shorts) for bf16 Spq
#define Z2S 69    // LDS stride (floats) for z2

typedef __attribute__((ext_vector_type(8))) short short8;
typedef __attribute__((ext_vector_type(4))) float f32x4;

__device__ inline float bflo(unsigned int v) { return __uint_as_float(v << 16); }
__device__ inline float bfhi(unsigned int v) { return __uint_as_float(v & 0xffff0000u); }
__device__ inline float bf2f(unsigned short v) { return __uint_as_float(((unsigned int)v) << 16); }

// single-instruction bf16 pair pack (RNE)
__device__ inline unsigned int cvtpk(float lo, float hi) {
    unsigned int r;
    asm("v_cvt_pk_bf16_f32 %0, %1, %2" : "=v"(r) : "v"(lo), "v"(hi));
    return r;
}
__device__ inline unsigned short f2bf1(float f) {
    unsigned int r;
    asm("v_cvt_pk_bf16_f32 %0, %1, %1" : "=v"(r) : "v"(f));
    return (unsigned short)r;
}

// column-interleave permutation: storage col for logical col L.
__device__ inline int permcol(int T, int lm) {   // T = logical tile (0..7)
    return 32 * (T >> 1) + 2 * lm + (T & 1);
}
// inverse: logical row for storage row k (for Wc2 K-dim pack)
__device__ inline int kperm(int k) {
    int u = k >> 1;
    return 32 * (u >> 4) + (u & 15) + ((k & 1) << 4);
}

// ---------------- graph build ----------------

__global__ void count_kernel(const int* __restrict__ col, int E, int* __restrict__ cnt) {
    int e = blockIdx.x * blockDim.x + threadIdx.x;
    if (e < E) atomicAdd(&cnt[col[e]], 1);
}

__global__ void scan_sum_kernel(const int* __restrict__ cnt, int N, int* __restrict__ bsum) {
    int b = blockIdx.x, t = threadIdx.x;
    int base = b * 1024 + t * 4;
    int s = 0;
#pragma unroll
    for (int g = 0; g < 4; ++g) {
        int i = base + g;
        if (i < N) s += cnt[i];
    }
    for (int off = 32; off >= 1; off >>= 1) s += __shfl_down(s, off, 64);
    __shared__ int ws[4];
    if ((t & 63) == 0) ws[t >> 6] = s;
    __syncthreads();
    if (t == 0) bsum[b] = ws[0] + ws[1] + ws[2] + ws[3];
}

__global__ void scan_offsets_kernel(const int* __restrict__ bsum, int nb,
                                    int* __restrict__ boff, int* __restrict__ col_start, int N) {
    int lane = threadIdx.x;
    int v = (lane < nb) ? bsum[lane] : 0;
    int incl = v;
    for (int off = 1; off < 64; off <<= 1) {
        int u = __shfl_up(incl, off, 64);
        if (lane >= off) incl += u;
    }
    if (lane < nb) boff[lane] = incl - v;
    if (lane == 63) col_start[N] = incl;
}

// also emits xs = dinv-prescaled x rows (folds dinv into the layer-1 gather source)
__global__ void scan_write_kernel(const int* __restrict__ cnt, int N, const int* __restrict__ boff,
                                  int* __restrict__ col_start, int* __restrict__ cursor,
                                  float* __restrict__ dinv,
                                  const float* __restrict__ x, float* __restrict__ xs) {
    int b = blockIdx.x, t = threadIdx.x;
    int lane = t & 63, wv = t >> 6;
    int base = b * 1024 + t * 4;
    int c[4];
    int s = 0;
#pragma unroll
    for (int g = 0; g < 4; ++g) {
        int i = base + g;
        c[g] = (i < N) ? cnt[i] : 0;
        s += c[g];
    }
    int incl = s;
    for (int off = 1; off < 64; off <<= 1) {
        int u = __shfl_up(incl, off, 64);
        if (lane >= off) incl += u;
    }
    __shared__ int ws[4];
    if (lane == 63) ws[wv] = incl;
    __syncthreads();
    int run = boff[b] + incl - s;
    for (int w = 0; w < wv; ++w) run += ws[w];
#pragma unroll
    for (int g = 0; g < 4; ++g) {
        int i = base + g;
        if (i < N) {
            col_start[i] = run;
            cursor[i] = run;
            float di = rsqrtf((float)(c[g] + 1));
            dinv[i] = di;
            float4 xa = ((const float4*)x)[i * 2];
            float4 xb = ((const float4*)x)[i * 2 + 1];
            xa.x *= di; xa.y *= di; xa.z *= di; xa.w *= di;
            xb.x *= di; xb.y *= di; xb.z *= di; xb.w *= di;
            ((float4*)xs)[i * 2] = xa;
            ((float4*)xs)[i * 2 + 1] = xb;
            run += c[g];
        }
    }
}

__global__ void scatter_kernel(const int* __restrict__ row, const int* __restrict__ col, int E,
                               int* __restrict__ cursor, int* __restrict__ csc_src,
                               int2* __restrict__ csc_ec) {
    int e = blockIdx.x * blockDim.x + threadIdx.x;
    if (e < E) {
        int c = col[e];
        int p = atomicAdd(&cursor[c], 1);
        csc_src[p] = row[e];
        csc_ec[p] = make_int2(e, c);
    }
}

// ---------------- GCN: aggregate-then-transform (bf16 dinv-prescaled features) ----------------

// wave-per-node aggregation on prescaled xs: 1 gather per neighbor (no dinv gather)
__global__ __launch_bounds__(256) void aggx_kernel(
    const float* __restrict__ xs, const int* __restrict__ col_start,
    const int* __restrict__ csc_src, const float* __restrict__ dinv,
    float* __restrict__ aggx, int N) {
    int wv = threadIdx.x >> 6, lane = threadIdx.x & 63;
    int i = blockIdx.x * 4 + wv;
    if (i >= N) return;
    int f = lane & 7, j = lane >> 3;
    int s0 = col_start[i], s1 = col_start[i + 1];
    float acc = 0.f;
    int p = s0 + j;
    for (; p + 8 < s1; p += 16) {
        int sa = csc_src[p], sb = csc_src[p + 8];
        acc += xs[sa * 8 + f] + xs[sb * 8 + f];
    }
    if (p < s1)
        acc += xs[csc_src[p] * 8 + f];
    acc += __shfl_xor(acc, 8, 64);
    acc += __shfl_xor(acc, 16, 64);
    acc += __shfl_xor(acc, 32, 64);
    if (j == 0) {
        float di = dinv[i];
        aggx[i * 8 + f] = di * (acc + xs[i * 8 + f]);
    }
}

__global__ void xform8bf_kernel(const float* __restrict__ aggx, const float* __restrict__ W,
                                const float* __restrict__ b, const float* __restrict__ dinv,
                                unsigned int* __restrict__ out, int N) {
    int t = blockIdx.x * 256 + threadIdx.x;
    int i = t >> 6, jp = t & 63;
    if (i >= N) return;
    const float* ar = aggx + i * 8;
    float sc = dinv[i];
    int j0 = jp * 2;
    float a0 = b[j0], a1 = b[j0 + 1];
#pragma unroll
    for (int k = 0; k < 8; ++k) {
        float av = ar[k];
        a0 = fmaf(av, W[k * 128 + j0], a0);
        a1 = fmaf(av, W[k * 128 + j0 + 1], a1);
    }
    out[(size_t)i * 64 + jp] = cvtpk(sc * fmaxf(a0, 0.f), sc * fmaxf(a1, 0.f));
}

// wave-per-node row-sum of prescaled bf16 rows; 16 row loads in flight per batch
// (r3 form: simple 16-deep MLP, no explicit index pipeline — pipelining regressed
//  due to +32 live VGPRs in a latency-bound kernel)
__global__ __launch_bounds__(256) void agg128bf_kernel(
    const unsigned int* __restrict__ hd, const int* __restrict__ col_start,
    const int* __restrict__ csc_src, const float* __restrict__ dinv,
    unsigned int* __restrict__ out, int N) {
    int wv = threadIdx.x >> 6, lane = threadIdx.x & 63;
    int i = blockIdx.x * 4 + wv;
    if (i >= N) return;
    int s0 = col_start[i], s1 = col_start[i + 1];
    float ax = 0.f, ay = 0.f;
    int p = s0;
    for (; p + 16 <= s1; p += 16) {
        unsigned int v[16];
#pragma unroll
        for (int k = 0; k < 16; ++k)
            v[k] = hd[(size_t)csc_src[p + k] * 64 + lane];
#pragma unroll
        for (int k = 0; k < 16; ++k) { ax += bflo(v[k]); ay += bfhi(v[k]); }
    }
    for (; p + 4 <= s1; p += 4) {
        unsigned int v0 = hd[(size_t)csc_src[p + 0] * 64 + lane];
        unsigned int v1 = hd[(size_t)csc_src[p + 1] * 64 + lane];
        unsigned int v2 = hd[(size_t)csc_src[p + 2] * 64 + lane];
        unsigned int v3 = hd[(size_t)csc_src[p + 3] * 64 + lane];
        ax += bflo(v0) + bflo(v1) + bflo(v2) + bflo(v3);
        ay += bfhi(v0) + bfhi(v1) + bfhi(v2) + bfhi(v3);
    }
    for (; p < s1; ++p) {
        unsigned int v = hd[(size_t)csc_src[p] * 64 + lane];
        ax += bflo(v); ay += bfhi(v);
    }
    float di = dinv[i];
    unsigned int vs = hd[(size_t)i * 64 + lane];
    float rx = di * (ax + bflo(vs));
    float ry = di * (ay + bfhi(vs));
    out[(size_t)i * 64 + lane] = cvtpk(rx, ry);
}

__global__ __launch_bounds__(256) void xform_mfma_kernel(
    const unsigned short* __restrict__ in, const unsigned short* __restrict__ Bp,
    const float* __restrict__ b, const float* __restrict__ scale,
    unsigned short* __restrict__ out, int N) {
    __shared__ __align__(16) unsigned short sm[64 * STC];
    int tid = threadIdx.x;
    int i0 = blockIdx.x * 64;
    for (int u = tid; u < 1024; u += 256) {
        int i = u >> 4, l = u & 15;
        int node = i0 + i; if (node >= N) node = N - 1;
        uint4 v = ((const uint4*)in)[(size_t)node * 16 + l];
        *(uint4*)&sm[i * STC + l * 8] = v;
    }
    __syncthreads();
    int lane = tid & 63, w = tid >> 6, lm = lane & 15, quad = lane >> 4;
    int nt0 = 2 * w, nt1 = 2 * w + 1;
    f32x4 acc0[4], acc1[4];
    {
        float bv0 = b[nt0 * 16 + lm], bv1 = b[nt1 * 16 + lm];
        for (int m = 0; m < 4; ++m)
            for (int r = 0; r < 4; ++r) { acc0[m][r] = bv0; acc1[m][r] = bv1; }
    }
#pragma unroll
    for (int s = 0; s < 4; ++s) {
        short8 b0 = *(const short8*)&Bp[((size_t)(s * 8 + nt0) * 64 + lane) * 8];
        short8 b1 = *(const short8*)&Bp[((size_t)(s * 8 + nt1) * 64 + lane) * 8];
#pragma unroll
        for (int m = 0; m < 4; ++m) {
            short8 afr = *(const short8*)&sm[(m * 16 + lm) * STC + s * 32 + quad * 8];
            acc0[m] = __builtin_amdgcn_mfma_f32_16x16x32_bf16(afr, b0, acc0[m], 0, 0, 0);
            acc1[m] = __builtin_amdgcn_mfma_f32_16x16x32_bf16(afr, b1, acc1[m], 0, 0, 0);
        }
    }
    __syncthreads();
    for (int m = 0; m < 4; ++m)
        for (int r = 0; r < 4; ++r) {
            int rw = m * 16 + quad * 4 + r;
            int node = i0 + rw; if (node >= N) node = N - 1;
            float sc = scale ? scale[node] : 1.f;
            sm[rw * SOT + nt0 * 16 + lm] = f2bf1(sc * fmaxf(acc0[m][r], 0.f));
            sm[rw * SOT + nt1 * 16 + lm] = f2bf1(sc * fmaxf(acc1[m][r], 0.f));
        }
    __syncthreads();
    for (int u = tid; u < 1024; u += 256) {
        int i = u >> 4, l = u & 15;
        int node = i0 + i;
        if (node < N)
            *(uint4*)&out[(size_t)node * 128 + l * 8] = *(uint4*)&sm[i * SOT + l * 8];
    }
}

// ---------------- classifier weight prep ----------------

__global__ void weff_kernel(const float* __restrict__ We2, const float* __restrict__ Wc1,
                            float* __restrict__ Weff) {
    int idx = blockIdx.x * blockDim.x + threadIdx.x;
    int k = idx >> 7, c = idx & 127;
    float acc = 0.f;
    for (int j = 0; j < 128; ++j)
        acc = fmaf(We2[k * 128 + j], Wc1[(256 + j) * 128 + c], acc);
    Weff[idx] = acc;
}

__global__ void bc1p_kernel(const float* __restrict__ bc1, const float* __restrict__ be2,
                            const float* __restrict__ Wc1, float* __restrict__ bc1p) {
    int c = threadIdx.x;
    float acc = bc1[c];
    for (int j = 0; j < 128; ++j)
        acc = fmaf(be2[j], Wc1[(256 + j) * 128 + c], acc);
    bc1p[c] = acc;
}

__global__ void packg_kernel(const float* __restrict__ src, unsigned short* __restrict__ dst) {
    int idx = blockIdx.x * 256 + threadIdx.x;  // 2048
    int s = idx >> 9, nt = (idx >> 6) & 7, lane = idx & 63;
    int quad = lane >> 4, lm = lane & 15;
    int n = nt * 16 + lm, k0 = s * 32 + quad * 8;
    unsigned int p[4];
#pragma unroll
    for (int g = 0; g < 4; ++g)
        p[g] = cvtpk(src[(k0 + 2 * g) * 128 + n], src[(k0 + 2 * g + 1) * 128 + n]);
    *(uint4*)&dst[(size_t)idx * 8] = make_uint4(p[0], p[1], p[2], p[3]);
}

// Wc2 pack with K-rows permuted to match interleaved z1 storage order
__global__ void pack2_kernel(const float* __restrict__ Wc2, unsigned short* __restrict__ Bp2) {
    int idx = blockIdx.x * 256 + threadIdx.x;  // 1024
    int s = idx >> 8, nt = (idx >> 6) & 3, lane = idx & 63;
    int quad = lane >> 4, lm = lane & 15;
    int n = nt * 16 + lm, k0 = s * 32 + quad * 8;
    unsigned int p[4];
#pragma unroll
    for (int g = 0; g < 4; ++g)
        p[g] = cvtpk(Wc2[kperm(k0 + 2 * g) * 64 + n], Wc2[kperm(k0 + 2 * g + 1) * 64 + n]);
    *(uint4*)&Bp2[(size_t)idx * 8] = make_uint4(p[0], p[1], p[2], p[3]);
}

__global__ void packwe1_kernel(const float* __restrict__ We1, const float* __restrict__ be1,
                               unsigned short* __restrict__ BpE) {
    int idx = blockIdx.x * 256 + threadIdx.x;  // 512
    if (idx >= 512) return;
    int nt = idx >> 6, lane = idx & 63;
    int quad = lane >> 4, lm = lane & 15;
    int n = nt * 16 + lm, k0 = quad * 8;
    unsigned int p[4];
#pragma unroll
    for (int g = 0; g < 4; ++g) {
        int r0 = k0 + 2 * g, r1 = r0 + 1;
        float v0 = (r0 < 4) ? We1[r0 * 128 + n] : ((r0 == 4) ? be1[n] : 0.f);
        float v1 = (r1 < 4) ? We1[r1 * 128 + n] : ((r1 == 4) ? be1[n] : 0.f);
        p[g] = cvtpk(v0, v1);
    }
    *(uint4*)&BpE[(size_t)idx * 8] = make_uint4(p[0], p[1], p[2], p[3]);
}

// ---------------- fused h3 transform + P/Q precompute ----------------

__global__ __launch_bounds__(256) void h3pq_kernel(
    const unsigned short* __restrict__ in, const unsigned short* __restrict__ BpW3,
    const float* __restrict__ b3,
    const unsigned short* __restrict__ BpA, const unsigned short* __restrict__ BpB,
    const float* __restrict__ bc1p,
    unsigned short* __restrict__ P, unsigned short* __restrict__ Q, int N) {
    __shared__ __align__(16) unsigned short At[64 * STC];
    __shared__ __align__(16) unsigned short Hs[64 * SOT];
    int tid = threadIdx.x;
    int i0 = blockIdx.x * 64;
    for (int u = tid; u < 1024; u += 256) {
        int i = u >> 4, l = u & 15;
        int node = i0 + i; if (node >= N) node = N - 1;
        uint4 v = ((const uint4*)in)[(size_t)node * 16 + l];
        *(uint4*)&At[i * STC + l * 8] = v;
    }
    __syncthreads();
    int lane = tid & 63, w = tid >> 6, lm = lane & 15, quad = lane >> 4;

    {
        int nt0 = 2 * w, nt1 = 2 * w + 1;
        f32x4 a0[4], a1[4];
        float bv0 = b3[nt0 * 16 + lm], bv1 = b3[nt1 * 16 + lm];
        for (int m = 0; m < 4; ++m)
            for (int r = 0; r < 4; ++r) { a0[m][r] = bv0; a1[m][r] = bv1; }
#pragma unroll
        for (int s = 0; s < 4; ++s) {
            short8 b0 = *(const short8*)&BpW3[((size_t)(s * 8 + nt0) * 64 + lane) * 8];
            short8 b1 = *(const short8*)&BpW3[((size_t)(s * 8 + nt1) * 64 + lane) * 8];
#pragma unroll
            for (int m = 0; m < 4; ++m) {
                short8 afr = *(const short8*)&At[(m * 16 + lm) * STC + s * 32 + quad * 8];
                a0[m] = __builtin_amdgcn_mfma_f32_16x16x32_bf16(afr, b0, a0[m], 0, 0, 0);
                a1[m] = __builtin_amdgcn_mfma_f32_16x16x32_bf16(afr, b1, a1[m], 0, 0, 0);
            }
        }
        __syncthreads();
        for (int m = 0; m < 4; ++m)
            for (int r = 0; r < 4; ++r) {
                int rw = m * 16 + quad * 4 + r;
                Hs[rw * SOT + nt0 * 16 + lm] = f2bf1(fmaxf(a0[m][r], 0.f));
                Hs[rw * SOT + nt1 * 16 + lm] = f2bf1(fmaxf(a1[m][r], 0.f));
            }
    }
    __syncthreads();

    int half = w & 1;
    const unsigned short* Bp = (w >> 1) ? BpB : BpA;
    f32x4 acc[4][4];
    for (int nt = 0; nt < 4; ++nt) {
        float bv = (w >> 1) ? 0.f : bc1p[half * 64 + nt * 16 + lm];
        for (int m = 0; m < 4; ++m)
            for (int r = 0; r < 4; ++r) acc[nt][m][r] = bv;
    }
#pragma unroll
    for (int s = 0; s < 4; ++s) {
        short8 afr[4];
#pragma unroll
        for (int m = 0; m < 4; ++m)
            afr[m] = *(const short8*)&Hs[(m * 16 + lm) * SOT + s * 32 + quad * 8];
#pragma unroll
        for (int nt = 0; nt < 4; ++nt) {
            short8 bfr = *(const short8*)&Bp[((size_t)(s * 8 + half * 4 + nt) * 64 + lane) * 8];
#pragma unroll
            for (int m = 0; m < 4; ++m)
                acc[nt][m] = __builtin_amdgcn_mfma_f32_16x16x32_bf16(afr[m], bfr, acc[nt][m], 0, 0, 0);
        }
    }
    __syncthreads();   // Hs fragment reads complete; At input dead since phase-1

    // P-waves (w<2) stage into At, Q-waves (w>=2) stage into Hs — concurrently,
    // then both global dumps after ONE barrier (was: 2 serialized write+dump phases)
    {
        unsigned short* St = (w < 2) ? At : Hs;
        int sstride = (w < 2) ? SOT : SOT;  // both staged at SOT stride
        for (int nt = 0; nt < 4; ++nt) {
            int T = half * 4 + nt;
            int pc = permcol(T, lm);
            for (int m = 0; m < 4; ++m)
                for (int r = 0; r < 4; ++r) {
                    int rw = m * 16 + quad * 4 + r;
                    St[rw * sstride + pc] = f2bf1(acc[nt][m][r]);
                }
        }
    }
    __syncthreads();
    for (int u = tid; u < 1024; u += 256) {
        int i = u >> 4, l = u & 15;
        int node = i0 + i;
        if (node < N) {
            *(uint4*)&P[(size_t)node * 128 + l * 8] = *(uint4*)&At[i * SOT + l * 8];
            *(uint4*)&Q[(size_t)node * 128 + l * 8] = *(uint4*)&Hs[i * SOT + l * 8];
        }
    }
}

// ---------------- fused classifier, all-MFMA (1 tile/block; interleaved Spq/z1; post-MFMA add-back) ----------------

__global__ __launch_bounds__(256, 4) void classifier_mfma2(
    const int* __restrict__ csc_src, const int2* __restrict__ csc_ec,
    const float* __restrict__ ea, const unsigned short* __restrict__ BpE,
    const unsigned short* __restrict__ P, const unsigned short* __restrict__ Q,
    const unsigned short* __restrict__ BpU, const unsigned short* __restrict__ Bp2,
    const float* __restrict__ bc2, const float* __restrict__ Wc3, const float* __restrict__ bc3,
    float* __restrict__ out, int E) {
    __shared__ __align__(16) unsigned char smem[37888];
    unsigned short* SpqB = (unsigned short*)smem;         // [64][SPQ] bf16 (interleaved cols)
    float* z2 = (float*)smem;                             // [64][Z2S] fp32 (overlay)
    unsigned short* At = (unsigned short*)(smem + 17664); // [64][STC] bf16 (t, then z1)
    unsigned short* z1 = At;                              // overlay
    float* part = (float*)(smem + 17664);                 // [4][64] (overlay)
    int* sS = (int*)(smem + 37120);
    int* eS = sS + 64;
    int* cS = eS + 64;

    int tid = threadIdx.x;
    int lane = tid & 63, w = tid >> 6, lm = lane & 15, quad = lane >> 4;
    int e0 = blockIdx.x * 64;

    short8 bE0 = *(const short8*)&BpE[((size_t)(2 * w) * 64 + lane) * 8];
    short8 bE1 = *(const short8*)&BpE[((size_t)(2 * w + 1) * 64 + lane) * 8];
    short8 b0s[4], b1s[4], b2s[4];
#pragma unroll
    for (int s = 0; s < 4; ++s) {
        b0s[s] = *(const short8*)&BpU[((size_t)(s * 8 + 2 * w) * 64 + lane) * 8];
        b1s[s] = *(const short8*)&BpU[((size_t)(s * 8 + 2 * w + 1) * 64 + lane) * 8];
        b2s[s] = *(const short8*)&Bp2[((size_t)(s * 4 + w) * 64 + lane) * 8];
    }
    float bv2 = bc2[w * 16 + lm];

    if (tid < 64) {
        int p = e0 + tid; if (p >= E) p = E - 1;
        sS[tid] = csc_src[p];
        int2 ec = csc_ec[p];
        eS[tid] = ec.x; cS[tid] = ec.y;
    }
    __syncthreads();

    // ---- issue ALL first-phase gathers before any conversion work ----
    float4 av[4];
    if (quad == 0) {
#pragma unroll
        for (int m = 0; m < 4; ++m)
            av[m] = ((const float4*)ea)[eS[m * 16 + lm]];
    }

    {
        const uint4* P4 = (const uint4*)P;
        const uint4* Q4 = (const uint4*)Q;
        int l = tid & 15;
        uint4 pv[4], qv[4];
#pragma unroll
        for (int j = 0; j < 4; ++j) {
            int i = (tid >> 4) + 16 * j;
            pv[j] = P4[(size_t)sS[i] * 16 + l];
            qv[j] = Q4[(size_t)cS[i] * 16 + l];
        }
#pragma unroll
        for (int j = 0; j < 4; ++j) {
            int i = (tid >> 4) + 16 * j;
            uint4 o;
            o.x = cvtpk(bflo(pv[j].x) + bflo(qv[j].x), bfhi(pv[j].x) + bfhi(qv[j].x));
            o.y = cvtpk(bflo(pv[j].y) + bflo(qv[j].y), bfhi(pv[j].y) + bfhi(qv[j].y));
            o.z = cvtpk(bflo(pv[j].z) + bflo(qv[j].z), bfhi(pv[j].z) + bfhi(qv[j].z));
            o.w = cvtpk(bflo(pv[j].w) + bflo(qv[j].w), bfhi(pv[j].w) + bfhi(qv[j].w));
            *(uint4*)&SpqB[i * SPQ + l * 8] = o;
        }
    }

    short8 eaf[4];
#pragma unroll
    for (int m = 0; m < 4; ++m) eaf[m] = (short8){0, 0, 0, 0, 0, 0, 0, 0};
    if (quad == 0) {
#pragma unroll
        for (int m = 0; m < 4; ++m) {
            eaf[m][0] = (short)f2bf1(av[m].x);
            eaf[m][1] = (short)f2bf1(av[m].y);
            eaf[m][2] = (short)f2bf1(av[m].z);
            eaf[m][3] = (short)f2bf1(av[m].w);
            eaf[m][4] = (short)0x3F80;  // 1.0 bf16
        }
    }

    {
        f32x4 zacc = {0.f, 0.f, 0.f, 0.f};
#pragma unroll
        for (int m = 0; m < 4; ++m) {
            f32x4 t0 = __builtin_amdgcn_mfma_f32_16x16x32_bf16(eaf[m], bE0, zacc, 0, 0, 0);
            f32x4 t1 = __builtin_amdgcn_mfma_f32_16x16x32_bf16(eaf[m], bE1, zacc, 0, 0, 0);
#pragma unroll
            for (int r = 0; r < 4; ++r) {
                int rw = m * 16 + quad * 4 + r;
                At[rw * STC + 32 * w + lm]      = f2bf1(fmaxf(t0[r], 0.f));
                At[rw * STC + 32 * w + 16 + lm] = f2bf1(fmaxf(t1[r], 0.f));
            }
        }
    }
    __syncthreads();

    f32x4 acc0[4], acc1[4];
    for (int m = 0; m < 4; ++m)
        for (int r = 0; r < 4; ++r) { acc0[m][r] = 0.f; acc1[m][r] = 0.f; }
#pragma unroll
    for (int s = 0; s < 4; ++s) {
#pragma unroll
        for (int m = 0; m < 4; ++m) {
            short8 afr = *(const short8*)&At[(m * 16 + lm) * STC + s * 32 + quad * 8];
            acc0[m] = __builtin_amdgcn_mfma_f32_16x16x32_bf16(afr, b0s[s], acc0[m], 0, 0, 0);
            acc1[m] = __builtin_amdgcn_mfma_f32_16x16x32_bf16(afr, b1s[s], acc1[m], 0, 0, 0);
        }
    }
    // add-back: one uint per (m,r) holds both acc0 (lo) and acc1 (hi) columns
    {
        const unsigned int* Spq32 = (const unsigned int*)SpqB;
        for (int m = 0; m < 4; ++m)
            for (int r = 0; r < 4; ++r) {
                int rw = m * 16 + quad * 4 + r;
                unsigned int pq = Spq32[rw * (SPQ / 2) + 16 * w + lm];
                acc0[m][r] = fmaxf(acc0[m][r] + bflo(pq), 0.f);
                acc1[m][r] = fmaxf(acc1[m][r] + bfhi(pq), 0.f);
            }
    }
    __syncthreads();
    {
        unsigned int* z1u = (unsigned int*)z1;
        for (int m = 0; m < 4; ++m)
            for (int r = 0; r < 4; ++r) {
                int rw = m * 16 + quad * 4 + r;
                z1u[rw * (STC / 2) + 16 * w + lm] = cvtpk(acc0[m][r], acc1[m][r]);
            }
    }
    __syncthreads();

    {
        f32x4 acc2[4];
        for (int m = 0; m < 4; ++m)
            for (int r = 0; r < 4; ++r) acc2[m][r] = bv2;
#pragma unroll
        for (int s = 0; s < 4; ++s) {
#pragma unroll
            for (int m = 0; m < 4; ++m) {
                short8 afr = *(const short8*)&z1[(m * 16 + lm) * STC + s * 32 + quad * 8];
                acc2[m] = __builtin_amdgcn_mfma_f32_16x16x32_bf16(afr, b2s[s], acc2[m], 0, 0, 0);
            }
        }
        for (int m = 0; m < 4; ++m)
            for (int r = 0; r < 4; ++r)
                z2[(m * 16 + quad * 4 + r) * Z2S + w * 16 + lm] = fmaxf(acc2[m][r], 0.f);
    }
    __syncthreads();

    {
        int e = tid & 63, q = tid >> 6;
        int c = q & 1, hf = q >> 1;
        const float* zr = z2 + e * Z2S + hf * 32;
        const float* wc = Wc3 + hf * 64 + c;
        float acc = 0.f;
#pragma unroll 8
        for (int kk = 0; kk < 32; ++kk)
            acc = fmaf(zr[kk], wc[2 * kk], acc);
        part[q * 64 + e] = acc;
    }
    __syncthreads();
    if (tid < 64) {
        int p = e0 + tid;
        if (p < E) {
            float l0 = bc3[0] + part[tid] + part[128 + tid];
            float l1 = bc3[1] + part[64 + tid] + part[192 + tid];
            float m = fmaxf(l0, l1);
            float lse = m + logf(expf(l0 - m) + expf(l1 - m));
            ((float2*)out)[eS[tid]] = make_float2(l0 - lse, l1 - lse);
        }
    }
}

// ---------------- launch ----------------

extern "C" void kernel_launch(void* const* d_in, const int* in_sizes, int n_in,
                              void* d_out, int out_size, void* d_ws, size_t ws_size,
                              hipStream_t stream) {
    const float* x   = (const float*)d_in[0];
    const int*   ei  = (const int*)d_in[1];
    const float* ea  = (const float*)d_in[2];
    const float* W1  = (const float*)d_in[3];
    const float* b1  = (const float*)d_in[4];
    const float* W2  = (const float*)d_in[5];
    const float* b2  = (const float*)d_in[6];
    const float* W3  = (const float*)d_in[7];
    const float* b3  = (const float*)d_in[8];
    const float* We1 = (const float*)d_in[9];
    const float* be1 = (const float*)d_in[10];
    const float* We2 = (const float*)d_in[11];
    const float* be2 = (const float*)d_in[12];
    const float* Wc1 = (const float*)d_in[13];
    const float* bc1 = (const float*)d_in[14];
    const float* Wc2 = (const float*)d_in[15];
    const float* bc2 = (const float*)d_in[16];
    const float* Wc3 = (const float*)d_in[17];
    const float* bc3 = (const float*)d_in[18];
    float* out = (float*)d_out;

    int N = in_sizes[0] / 8;
    int E = in_sizes[1] / 2;
    const int* row = ei;
    const int* col = ei + E;
    int NB = (N + 1023) / 1024;
    int ntiles = (E + 63) / 64;

    char* w = (char*)d_ws;
    auto alloc = [&](size_t bytes) { void* p = (void*)w; w += (bytes + 255) & ~(size_t)255; return p; };
    int*   cnt       = (int*)alloc((size_t)N * 4);
    int*   col_start = (int*)alloc((size_t)(N + 1) * 4);
    int*   cursor    = (int*)alloc((size_t)N * 4);
    int*   csc_src   = (int*)alloc((size_t)E * 4);
    int2*  csc_ec    = (int2*)alloc((size_t)E * 8);
    float* dinv      = (float*)alloc((size_t)N * 4);
    int*   bsum      = (int*)alloc(64 * 4);
    int*   boff      = (int*)alloc(64 * 4);
    float* Weff      = (float*)alloc(128 * 128 * 4);
    float* bc1p      = (float*)alloc(128 * 4);
    unsigned short* BpA  = (unsigned short*)alloc(32768);
    unsigned short* BpB  = (unsigned short*)alloc(32768);
    unsigned short* BpU  = (unsigned short*)alloc(32768);
    unsigned short* BpW2 = (unsigned short*)alloc(32768);
    unsigned short* BpW3 = (unsigned short*)alloc(32768);
    unsigned short* Bp2  = (unsigned short*)alloc(16384);
    unsigned short* BpE  = (unsigned short*)alloc(8192);
    float* aggx = (float*)alloc((size_t)N * 8 * 4);
    float* xs   = (float*)alloc((size_t)N * 8 * 4);
    unsigned short* bufA = (unsigned short*)alloc((size_t)N * H * 2);
    unsigned short* bufB = (unsigned short*)alloc((size_t)N * H * 2);
    unsigned short* Pm   = (unsigned short*)alloc((size_t)N * H * 2);
    unsigned short* Qm   = (unsigned short*)alloc((size_t)N * H * 2);

    // graph build (CSC with eid+col); scan_write also emits dinv-prescaled xs
    hipMemsetAsync(cnt, 0, (size_t)N * 4, stream);
    count_kernel<<<(E + 255) / 256, 256, 0, stream>>>(col, E, cnt);
    scan_sum_kernel<<<NB, 256, 0, stream>>>(cnt, N, bsum);
    scan_offsets_kernel<<<1, 64, 0, stream>>>(bsum, NB, boff, col_start, N);
    scan_write_kernel<<<NB, 256, 0, stream>>>(cnt, N, boff, col_start, cursor, dinv, x, xs);
    scatter_kernel<<<(E + 255) / 256, 256, 0, stream>>>(row, col, E, cursor, csc_src, csc_ec);

    // weight prep
    weff_kernel<<<64, 256, 0, stream>>>(We2, Wc1, Weff);
    bc1p_kernel<<<1, 128, 0, stream>>>(bc1, be2, Wc1, bc1p);
    packg_kernel<<<8, 256, 0, stream>>>(Wc1, BpA);
    packg_kernel<<<8, 256, 0, stream>>>(Wc1 + 128 * 128, BpB);
    packg_kernel<<<8, 256, 0, stream>>>(Weff, BpU);
    packg_kernel<<<8, 256, 0, stream>>>(W2, BpW2);
    packg_kernel<<<8, 256, 0, stream>>>(W3, BpW3);
    pack2_kernel<<<4, 256, 0, stream>>>(Wc2, Bp2);
    packwe1_kernel<<<2, 256, 0, stream>>>(We1, be1, BpE);

    // GCN: aggregate-then-transform, dinv-prescaled bf16 features
    aggx_kernel<<<(N + 3) / 4, 256, 0, stream>>>(xs, col_start, csc_src, dinv, aggx, N);
    xform8bf_kernel<<<(N * 64 + 255) / 256, 256, 0, stream>>>(aggx, W1, b1, dinv,
                                                              (unsigned int*)bufA, N);   // h1d
    agg128bf_kernel<<<(N + 3) / 4, 256, 0, stream>>>((const unsigned int*)bufA, col_start, csc_src,
                                                     dinv, (unsigned int*)bufB, N);      // agg2
    xform_mfma_kernel<<<(N + 63) / 64, 256, 0, stream>>>(bufB, BpW2, b2, dinv, bufA, N); // h2d
    agg128bf_kernel<<<(N + 3) / 4, 256, 0, stream>>>((const unsigned int*)bufA, col_start, csc_src,
                                                     dinv, (unsigned int*)bufB, N);      // agg3
    h3pq_kernel<<<(N + 63) / 64, 256, 0, stream>>>(bufB, BpW3, b3, BpA, BpB, bc1p, Pm, Qm, N);

    // fused all-MFMA classifier in CSC order (1 tile/block)
    classifier_mfma2<<<ntiles, 256, 0, stream>>>(
        csc_src, csc_ec, ea, BpE, Pm, Qm, BpU, Bp2, bc2, Wc3, bc3, out, E);
}

// Round 9
// 414.512 us; speedup vs baseline: 1.0870x; 1.0569x over previous
//
#include <hip/hip_runtime.h>
#include <math.h>

#define H 128
#define STC 152   // LDS stride (shorts) for bf16 A-tiles
#define SOT 136   // LDS stride (shorts) for staged bf16 output tiles
#define SPQ 136   // LDS stride (shorts) for bf16 Spq
#define Z2S 69    // LDS stride (floats) for z2

typedef __attribute__((ext_vector_type(8))) short short8;
typedef __attribute__((ext_vector_type(4))) float f32x4;

__device__ inline float bflo(unsigned int v) { return __uint_as_float(v << 16); }
__device__ inline float bfhi(unsigned int v) { return __uint_as_float(v & 0xffff0000u); }
__device__ inline float bf2f(unsigned short v) { return __uint_as_float(((unsigned int)v) << 16); }

// single-instruction bf16 pair pack (RNE)
__device__ inline unsigned int cvtpk(float lo, float hi) {
    unsigned int r;
    asm("v_cvt_pk_bf16_f32 %0, %1, %2" : "=v"(r) : "v"(lo), "v"(hi));
    return r;
}
__device__ inline unsigned short f2bf1(float f) {
    unsigned int r;
    asm("v_cvt_pk_bf16_f32 %0, %1, %1" : "=v"(r) : "v"(f));
    return (unsigned short)r;
}

// column-interleave permutation: storage col for logical col L.
__device__ inline int permcol(int T, int lm) {   // T = logical tile (0..7)
    return 32 * (T >> 1) + 2 * lm + (T & 1);
}
// inverse: logical row for storage row k (for Wc2 K-dim pack)
__device__ inline int kperm(int k) {
    int u = k >> 1;
    return 32 * (u >> 4) + (u & 15) + ((k & 1) << 4);
}

// ---------------- graph build ----------------

__global__ void count_kernel(const int* __restrict__ col, int E, int* __restrict__ cnt) {
    int e = blockIdx.x * blockDim.x + threadIdx.x;
    if (e < E) atomicAdd(&cnt[col[e]], 1);
}

__global__ void scan_sum_kernel(const int* __restrict__ cnt, int N, int* __restrict__ bsum) {
    int b = blockIdx.x, t = threadIdx.x;
    int base = b * 1024 + t * 4;
    int s = 0;
#pragma unroll
    for (int g = 0; g < 4; ++g) {
        int i = base + g;
        if (i < N) s += cnt[i];
    }
    for (int off = 32; off >= 1; off >>= 1) s += __shfl_down(s, off, 64);
    __shared__ int ws[4];
    if ((t & 63) == 0) ws[t >> 6] = s;
    __syncthreads();
    if (t == 0) bsum[b] = ws[0] + ws[1] + ws[2] + ws[3];
}

__global__ void scan_offsets_kernel(const int* __restrict__ bsum, int nb,
                                    int* __restrict__ boff, int* __restrict__ col_start, int N) {
    int lane = threadIdx.x;
    int v = (lane < nb) ? bsum[lane] : 0;
    int incl = v;
    for (int off = 1; off < 64; off <<= 1) {
        int u = __shfl_up(incl, off, 64);
        if (lane >= off) incl += u;
    }
    if (lane < nb) boff[lane] = incl - v;
    if (lane == 63) col_start[N] = incl;
}

// also emits xs = dinv-prescaled x rows (folds dinv into the layer-1 gather source)
__global__ void scan_write_kernel(const int* __restrict__ cnt, int N, const int* __restrict__ boff,
                                  int* __restrict__ col_start, int* __restrict__ cursor,
                                  float* __restrict__ dinv,
                                  const float* __restrict__ x, float* __restrict__ xs) {
    int b = blockIdx.x, t = threadIdx.x;
    int lane = t & 63, wv = t >> 6;
    int base = b * 1024 + t * 4;
    int c[4];
    int s = 0;
#pragma unroll
    for (int g = 0; g < 4; ++g) {
        int i = base + g;
        c[g] = (i < N) ? cnt[i] : 0;
        s += c[g];
    }
    int incl = s;
    for (int off = 1; off < 64; off <<= 1) {
        int u = __shfl_up(incl, off, 64);
        if (lane >= off) incl += u;
    }
    __shared__ int ws[4];
    if (lane == 63) ws[wv] = incl;
    __syncthreads();
    int run = boff[b] + incl - s;
    for (int w = 0; w < wv; ++w) run += ws[w];
#pragma unroll
    for (int g = 0; g < 4; ++g) {
        int i = base + g;
        if (i < N) {
            col_start[i] = run;
            cursor[i] = run;
            float di = rsqrtf((float)(c[g] + 1));
            dinv[i] = di;
            float4 xa = ((const float4*)x)[i * 2];
            float4 xb = ((const float4*)x)[i * 2 + 1];
            xa.x *= di; xa.y *= di; xa.z *= di; xa.w *= di;
            xb.x *= di; xb.y *= di; xb.z *= di; xb.w *= di;
            ((float4*)xs)[i * 2] = xa;
            ((float4*)xs)[i * 2 + 1] = xb;
            run += c[g];
        }
    }
}

__global__ void scatter_kernel(const int* __restrict__ row, const int* __restrict__ col, int E,
                               int* __restrict__ cursor, int* __restrict__ csc_src,
                               int2* __restrict__ csc_ec) {
    int e = blockIdx.x * blockDim.x + threadIdx.x;
    if (e < E) {
        int c = col[e];
        int p = atomicAdd(&cursor[c], 1);
        csc_src[p] = row[e];
        csc_ec[p] = make_int2(e, c);
    }
}

// ---------------- GCN layer 1: fused aggregate + 8->128 transform ----------------

// wave-per-node; after the xor-reduce every lane holds the full sum for f=lane&7,
// 8 shuffles broadcast the feature vector, then each lane computes 2 of 128 outputs.
__global__ __launch_bounds__(256) void agg1x_kernel(
    const float* __restrict__ xs, const int* __restrict__ col_start,
    const int* __restrict__ csc_src, const float* __restrict__ dinv,
    const float* __restrict__ W, const float* __restrict__ b,
    unsigned int* __restrict__ out, int N) {
    int wv = threadIdx.x >> 6, lane = threadIdx.x & 63;
    int i = blockIdx.x * 4 + wv;
    if (i >= N) return;
    int f = lane & 7;
    int s0 = col_start[i], s1 = col_start[i + 1];
    float acc = 0.f;
    int p = s0 + (lane >> 3);
    for (; p + 8 < s1; p += 16) {
        int sa = csc_src[p], sb = csc_src[p + 8];
        acc += xs[sa * 8 + f] + xs[sb * 8 + f];
    }
    if (p < s1)
        acc += xs[csc_src[p] * 8 + f];
    acc += __shfl_xor(acc, 8, 64);
    acc += __shfl_xor(acc, 16, 64);
    acc += __shfl_xor(acc, 32, 64);
    float di = dinv[i];
    float av = di * (acc + xs[i * 8 + f]);   // full agg value for feature f, all lanes
    float afv[8];
#pragma unroll
    for (int k = 0; k < 8; ++k) afv[k] = __shfl(av, k, 64);
    int j0 = 2 * lane;
    float a0 = b[j0], a1 = b[j0 + 1];
#pragma unroll
    for (int k = 0; k < 8; ++k) {
        a0 = fmaf(afv[k], W[k * 128 + j0], a0);
        a1 = fmaf(afv[k], W[k * 128 + j0 + 1], a1);
    }
    out[(size_t)i * 64 + lane] = cvtpk(di * fmaxf(a0, 0.f), di * fmaxf(a1, 0.f));
}

// wave-per-node row-sum of prescaled bf16 rows; 16 row loads in flight per batch
__global__ __launch_bounds__(256) void agg128bf_kernel(
    const unsigned int* __restrict__ hd, const int* __restrict__ col_start,
    const int* __restrict__ csc_src, const float* __restrict__ dinv,
    unsigned int* __restrict__ out, int N) {
    int wv = threadIdx.x >> 6, lane = threadIdx.x & 63;
    int i = blockIdx.x * 4 + wv;
    if (i >= N) return;
    int s0 = col_start[i], s1 = col_start[i + 1];
    float ax = 0.f, ay = 0.f;
    int p = s0;
    for (; p + 16 <= s1; p += 16) {
        unsigned int v[16];
#pragma unroll
        for (int k = 0; k < 16; ++k)
            v[k] = hd[(size_t)csc_src[p + k] * 64 + lane];
#pragma unroll
        for (int k = 0; k < 16; ++k) { ax += bflo(v[k]); ay += bfhi(v[k]); }
    }
    for (; p + 4 <= s1; p += 4) {
        unsigned int v0 = hd[(size_t)csc_src[p + 0] * 64 + lane];
        unsigned int v1 = hd[(size_t)csc_src[p + 1] * 64 + lane];
        unsigned int v2 = hd[(size_t)csc_src[p + 2] * 64 + lane];
        unsigned int v3 = hd[(size_t)csc_src[p + 3] * 64 + lane];
        ax += bflo(v0) + bflo(v1) + bflo(v2) + bflo(v3);
        ay += bfhi(v0) + bfhi(v1) + bfhi(v2) + bfhi(v3);
    }
    for (; p < s1; ++p) {
        unsigned int v = hd[(size_t)csc_src[p] * 64 + lane];
        ax += bflo(v); ay += bfhi(v);
    }
    float di = dinv[i];
    unsigned int vs = hd[(size_t)i * 64 + lane];
    float rx = di * (ax + bflo(vs));
    float ry = di * (ay + bfhi(vs));
    out[(size_t)i * 64 + lane] = cvtpk(rx, ry);
}

__global__ __launch_bounds__(256) void xform_mfma_kernel(
    const unsigned short* __restrict__ in, const unsigned short* __restrict__ Bp,
    const float* __restrict__ b, const float* __restrict__ scale,
    unsigned short* __restrict__ out, int N) {
    __shared__ __align__(16) unsigned short sm[64 * STC];
    int tid = threadIdx.x;
    int i0 = blockIdx.x * 64;
    for (int u = tid; u < 1024; u += 256) {
        int i = u >> 4, l = u & 15;
        int node = i0 + i; if (node >= N) node = N - 1;
        uint4 v = ((const uint4*)in)[(size_t)node * 16 + l];
        *(uint4*)&sm[i * STC + l * 8] = v;
    }
    __syncthreads();
    int lane = tid & 63, w = tid >> 6, lm = lane & 15, quad = lane >> 4;
    int nt0 = 2 * w, nt1 = 2 * w + 1;
    f32x4 acc0[4], acc1[4];
    {
        float bv0 = b[nt0 * 16 + lm], bv1 = b[nt1 * 16 + lm];
        for (int m = 0; m < 4; ++m)
            for (int r = 0; r < 4; ++r) { acc0[m][r] = bv0; acc1[m][r] = bv1; }
    }
#pragma unroll
    for (int s = 0; s < 4; ++s) {
        short8 b0 = *(const short8*)&Bp[((size_t)(s * 8 + nt0) * 64 + lane) * 8];
        short8 b1 = *(const short8*)&Bp[((size_t)(s * 8 + nt1) * 64 + lane) * 8];
#pragma unroll
        for (int m = 0; m < 4; ++m) {
            short8 afr = *(const short8*)&sm[(m * 16 + lm) * STC + s * 32 + quad * 8];
            acc0[m] = __builtin_amdgcn_mfma_f32_16x16x32_bf16(afr, b0, acc0[m], 0, 0, 0);
            acc1[m] = __builtin_amdgcn_mfma_f32_16x16x32_bf16(afr, b1, acc1[m], 0, 0, 0);
        }
    }
    __syncthreads();
    for (int m = 0; m < 4; ++m)
        for (int r = 0; r < 4; ++r) {
            int rw = m * 16 + quad * 4 + r;
            int node = i0 + rw; if (node >= N) node = N - 1;
            float sc = scale ? scale[node] : 1.f;
            sm[rw * SOT + nt0 * 16 + lm] = f2bf1(sc * fmaxf(acc0[m][r], 0.f));
            sm[rw * SOT + nt1 * 16 + lm] = f2bf1(sc * fmaxf(acc1[m][r], 0.f));
        }
    __syncthreads();
    for (int u = tid; u < 1024; u += 256) {
        int i = u >> 4, l = u & 15;
        int node = i0 + i;
        if (node < N)
            *(uint4*)&out[(size_t)node * 128 + l * 8] = *(uint4*)&sm[i * SOT + l * 8];
    }
}

// ---------------- classifier weight prep ----------------

__global__ void weff_kernel(const float* __restrict__ We2, const float* __restrict__ Wc1,
                            float* __restrict__ Weff) {
    int idx = blockIdx.x * blockDim.x + threadIdx.x;
    int k = idx >> 7, c = idx & 127;
    float acc = 0.f;
    for (int j = 0; j < 128; ++j)
        acc = fmaf(We2[k * 128 + j], Wc1[(256 + j) * 128 + c], acc);
    Weff[idx] = acc;
}

// all remaining weight prep in one launch: blocks 0..39 = packg x5 (8 blocks each),
// 40..43 = pack2 (Wc2, kperm'd), 44..45 = packwe1, 46 = bc1p
__global__ void prep_pack_kernel(
    const float* __restrict__ Wc1, const float* __restrict__ Weff,
    const float* __restrict__ W2, const float* __restrict__ W3,
    const float* __restrict__ Wc2, const float* __restrict__ We1,
    const float* __restrict__ be1, const float* __restrict__ bc1,
    const float* __restrict__ be2,
    unsigned short* __restrict__ BpA, unsigned short* __restrict__ BpB,
    unsigned short* __restrict__ BpU, unsigned short* __restrict__ BpW2,
    unsigned short* __restrict__ BpW3, unsigned short* __restrict__ Bp2,
    unsigned short* __restrict__ BpE, float* __restrict__ bc1p) {
    int b = blockIdx.x, tid = threadIdx.x;
    if (b < 40) {
        int which = b >> 3;
        const float* src = (which == 0) ? Wc1 : (which == 1) ? (Wc1 + 128 * 128)
                         : (which == 2) ? Weff : (which == 3) ? W2 : W3;
        unsigned short* dst = (which == 0) ? BpA : (which == 1) ? BpB
                            : (which == 2) ? BpU : (which == 3) ? BpW2 : BpW3;
        int idx = (b & 7) * 256 + tid;  // 0..2047
        int s = idx >> 9, nt = (idx >> 6) & 7, lane = idx & 63;
        int quad = lane >> 4, lm = lane & 15;
        int n = nt * 16 + lm, k0 = s * 32 + quad * 8;
        unsigned int p[4];
#pragma unroll
        for (int g = 0; g < 4; ++g)
            p[g] = cvtpk(src[(k0 + 2 * g) * 128 + n], src[(k0 + 2 * g + 1) * 128 + n]);
        *(uint4*)&dst[(size_t)idx * 8] = make_uint4(p[0], p[1], p[2], p[3]);
    } else if (b < 44) {
        int idx = (b - 40) * 256 + tid;  // 0..1023
        int s = idx >> 8, nt = (idx >> 6) & 3, lane = idx & 63;
        int quad = lane >> 4, lm = lane & 15;
        int n = nt * 16 + lm, k0 = s * 32 + quad * 8;
        unsigned int p[4];
#pragma unroll
        for (int g = 0; g < 4; ++g)
            p[g] = cvtpk(Wc2[kperm(k0 + 2 * g) * 64 + n], Wc2[kperm(k0 + 2 * g + 1) * 64 + n]);
        *(uint4*)&Bp2[(size_t)idx * 8] = make_uint4(p[0], p[1], p[2], p[3]);
    } else if (b < 46) {
        int idx = (b - 44) * 256 + tid;  // 0..511
        int nt = idx >> 6, lane = idx & 63;
        int quad = lane >> 4, lm = lane & 15;
        int n = nt * 16 + lm, k0 = quad * 8;
        unsigned int p[4];
#pragma unroll
        for (int g = 0; g < 4; ++g) {
            int r0 = k0 + 2 * g, r1 = r0 + 1;
            float v0 = (r0 < 4) ? We1[r0 * 128 + n] : ((r0 == 4) ? be1[n] : 0.f);
            float v1 = (r1 < 4) ? We1[r1 * 128 + n] : ((r1 == 4) ? be1[n] : 0.f);
            p[g] = cvtpk(v0, v1);
        }
        *(uint4*)&BpE[(size_t)idx * 8] = make_uint4(p[0], p[1], p[2], p[3]);
    } else {
        if (tid < 128) {
            float acc = bc1[tid];
            for (int j = 0; j < 128; ++j)
                acc = fmaf(be2[j], Wc1[(256 + j) * 128 + tid], acc);
            bc1p[tid] = acc;
        }
    }
}

// ---------------- fused h3 transform + P/Q precompute ----------------

__global__ __launch_bounds__(256) void h3pq_kernel(
    const unsigned short* __restrict__ in, const unsigned short* __restrict__ BpW3,
    const float* __restrict__ b3,
    const unsigned short* __restrict__ BpA, const unsigned short* __restrict__ BpB,
    const float* __restrict__ bc1p,
    unsigned short* __restrict__ P, unsigned short* __restrict__ Q, int N) {
    __shared__ __align__(16) unsigned short At[64 * STC];
    __shared__ __align__(16) unsigned short Hs[64 * SOT];
    int tid = threadIdx.x;
    int i0 = blockIdx.x * 64;
    for (int u = tid; u < 1024; u += 256) {
        int i = u >> 4, l = u & 15;
        int node = i0 + i; if (node >= N) node = N - 1;
        uint4 v = ((const uint4*)in)[(size_t)node * 16 + l];
        *(uint4*)&At[i * STC + l * 8] = v;
    }
    __syncthreads();
    int lane = tid & 63, w = tid >> 6, lm = lane & 15, quad = lane >> 4;

    {
        int nt0 = 2 * w, nt1 = 2 * w + 1;
        f32x4 a0[4], a1[4];
        float bv0 = b3[nt0 * 16 + lm], bv1 = b3[nt1 * 16 + lm];
        for (int m = 0; m < 4; ++m)
            for (int r = 0; r < 4; ++r) { a0[m][r] = bv0; a1[m][r] = bv1; }
#pragma unroll
        for (int s = 0; s < 4; ++s) {
            short8 b0 = *(const short8*)&BpW3[((size_t)(s * 8 + nt0) * 64 + lane) * 8];
            short8 b1 = *(const short8*)&BpW3[((size_t)(s * 8 + nt1) * 64 + lane) * 8];
#pragma unroll
            for (int m = 0; m < 4; ++m) {
                short8 afr = *(const short8*)&At[(m * 16 + lm) * STC + s * 32 + quad * 8];
                a0[m] = __builtin_amdgcn_mfma_f32_16x16x32_bf16(afr, b0, a0[m], 0, 0, 0);
                a1[m] = __builtin_amdgcn_mfma_f32_16x16x32_bf16(afr, b1, a1[m], 0, 0, 0);
            }
        }
        __syncthreads();
        for (int m = 0; m < 4; ++m)
            for (int r = 0; r < 4; ++r) {
                int rw = m * 16 + quad * 4 + r;
                Hs[rw * SOT + nt0 * 16 + lm] = f2bf1(fmaxf(a0[m][r], 0.f));
                Hs[rw * SOT + nt1 * 16 + lm] = f2bf1(fmaxf(a1[m][r], 0.f));
            }
    }
    __syncthreads();

    int half = w & 1;
    const unsigned short* Bp = (w >> 1) ? BpB : BpA;
    f32x4 acc[4][4];
    for (int nt = 0; nt < 4; ++nt) {
        float bv = (w >> 1) ? 0.f : bc1p[half * 64 + nt * 16 + lm];
        for (int m = 0; m < 4; ++m)
            for (int r = 0; r < 4; ++r) acc[nt][m][r] = bv;
    }
#pragma unroll
    for (int s = 0; s < 4; ++s) {
        short8 afr[4];
#pragma unroll
        for (int m = 0; m < 4; ++m)
            afr[m] = *(const short8*)&Hs[(m * 16 + lm) * SOT + s * 32 + quad * 8];
#pragma unroll
        for (int nt = 0; nt < 4; ++nt) {
            short8 bfr = *(const short8*)&Bp[((size_t)(s * 8 + half * 4 + nt) * 64 + lane) * 8];
#pragma unroll
            for (int m = 0; m < 4; ++m)
                acc[nt][m] = __builtin_amdgcn_mfma_f32_16x16x32_bf16(afr[m], bfr, acc[nt][m], 0, 0, 0);
        }
    }
    __syncthreads();   // Hs fragment reads complete; At input dead since phase-1

    // P-waves (w<2) stage into At, Q-waves (w>=2) stage into Hs — concurrently
    {
        unsigned short* St = (w < 2) ? At : Hs;
        for (int nt = 0; nt < 4; ++nt) {
            int T = half * 4 + nt;
            int pc = permcol(T, lm);
            for (int m = 0; m < 4; ++m)
                for (int r = 0; r < 4; ++r) {
                    int rw = m * 16 + quad * 4 + r;
                    St[rw * SOT + pc] = f2bf1(acc[nt][m][r]);
                }
        }
    }
    __syncthreads();
    for (int u = tid; u < 1024; u += 256) {
        int i = u >> 4, l = u & 15;
        int node = i0 + i;
        if (node < N) {
            *(uint4*)&P[(size_t)node * 128 + l * 8] = *(uint4*)&At[i * SOT + l * 8];
            *(uint4*)&Q[(size_t)node * 128 + l * 8] = *(uint4*)&Hs[i * SOT + l * 8];
        }
    }
}

// ---------------- fused classifier, all-MFMA (1 tile/block; interleaved Spq/z1; post-MFMA add-back) ----------------

__global__ __launch_bounds__(256, 4) void classifier_mfma2(
    const int* __restrict__ csc_src, const int2* __restrict__ csc_ec,
    const float* __restrict__ ea, const unsigned short* __restrict__ BpE,
    const unsigned short* __restrict__ P, const unsigned short* __restrict__ Q,
    const unsigned short* __restrict__ BpU, const unsigned short* __restrict__ Bp2,
    const float* __restrict__ bc2, const float* __restrict__ Wc3, const float* __restrict__ bc3,
    float* __restrict__ out, int E) {
    __shared__ __align__(16) unsigned char smem[37888];
    unsigned short* SpqB = (unsigned short*)smem;         // [64][SPQ] bf16 (interleaved cols)
    float* z2 = (float*)smem;                             // [64][Z2S] fp32 (overlay)
    unsigned short* At = (unsigned short*)(smem + 17664); // [64][STC] bf16 (t, then z1)
    unsigned short* z1 = At;                              // overlay
    float* part = (float*)(smem + 17664);                 // [4][64] (overlay)
    int* sS = (int*)(smem + 37120);
    int* eS = sS + 64;
    int* cS = eS + 64;

    int tid = threadIdx.x;
    int lane = tid & 63, w = tid >> 6, lm = lane & 15, quad = lane >> 4;
    int e0 = blockIdx.x * 64;

    short8 bE0 = *(const short8*)&BpE[((size_t)(2 * w) * 64 + lane) * 8];
    short8 bE1 = *(const short8*)&BpE[((size_t)(2 * w + 1) * 64 + lane) * 8];
    short8 b0s[4], b1s[4], b2s[4];
#pragma unroll
    for (int s = 0; s < 4; ++s) {
        b0s[s] = *(const short8*)&BpU[((size_t)(s * 8 + 2 * w) * 64 + lane) * 8];
        b1s[s] = *(const short8*)&BpU[((size_t)(s * 8 + 2 * w + 1) * 64 + lane) * 8];
        b2s[s] = *(const short8*)&Bp2[((size_t)(s * 4 + w) * 64 + lane) * 8];
    }
    float bv2 = bc2[w * 16 + lm];

    if (tid < 64) {
        int p = e0 + tid; if (p >= E) p = E - 1;
        sS[tid] = csc_src[p];
        int2 ec = csc_ec[p];
        eS[tid] = ec.x; cS[tid] = ec.y;
    }
    __syncthreads();

    // ---- issue ALL first-phase gathers before any conversion work ----
    float4 av[4];
    if (quad == 0) {
#pragma unroll
        for (int m = 0; m < 4; ++m)
            av[m] = ((const float4*)ea)[eS[m * 16 + lm]];
    }

    {
        const uint4* P4 = (const uint4*)P;
        const uint4* Q4 = (const uint4*)Q;
        int l = tid & 15;
        uint4 pv[4], qv[4];
#pragma unroll
        for (int j = 0; j < 4; ++j) {
            int i = (tid >> 4) + 16 * j;
            pv[j] = P4[(size_t)sS[i] * 16 + l];
            qv[j] = Q4[(size_t)cS[i] * 16 + l];
        }
#pragma unroll
        for (int j = 0; j < 4; ++j) {
            int i = (tid >> 4) + 16 * j;
            uint4 o;
            o.x = cvtpk(bflo(pv[j].x) + bflo(qv[j].x), bfhi(pv[j].x) + bfhi(qv[j].x));
            o.y = cvtpk(bflo(pv[j].y) + bflo(qv[j].y), bfhi(pv[j].y) + bfhi(qv[j].y));
            o.z = cvtpk(bflo(pv[j].z) + bflo(qv[j].z), bfhi(pv[j].z) + bfhi(qv[j].z));
            o.w = cvtpk(bflo(pv[j].w) + bflo(qv[j].w), bfhi(pv[j].w) + bfhi(qv[j].w));
            *(uint4*)&SpqB[i * SPQ + l * 8] = o;
        }
    }

    short8 eaf[4];
#pragma unroll
    for (int m = 0; m < 4; ++m) eaf[m] = (short8){0, 0, 0, 0, 0, 0, 0, 0};
    if (quad == 0) {
#pragma unroll
        for (int m = 0; m < 4; ++m) {
            eaf[m][0] = (short)f2bf1(av[m].x);
            eaf[m][1] = (short)f2bf1(av[m].y);
            eaf[m][2] = (short)f2bf1(av[m].z);
            eaf[m][3] = (short)f2bf1(av[m].w);
            eaf[m][4] = (short)0x3F80;  // 1.0 bf16
        }
    }

    {
        f32x4 zacc = {0.f, 0.f, 0.f, 0.f};
#pragma unroll
        for (int m = 0; m < 4; ++m) {
            f32x4 t0 = __builtin_amdgcn_mfma_f32_16x16x32_bf16(eaf[m], bE0, zacc, 0, 0, 0);
            f32x4 t1 = __builtin_amdgcn_mfma_f32_16x16x32_bf16(eaf[m], bE1, zacc, 0, 0, 0);
#pragma unroll
            for (int r = 0; r < 4; ++r) {
                int rw = m * 16 + quad * 4 + r;
                At[rw * STC + 32 * w + lm]      = f2bf1(fmaxf(t0[r], 0.f));
                At[rw * STC + 32 * w + 16 + lm] = f2bf1(fmaxf(t1[r], 0.f));
            }
        }
    }
    __syncthreads();

    f32x4 acc0[4], acc1[4];
    for (int m = 0; m < 4; ++m)
        for (int r = 0; r < 4; ++r) { acc0[m][r] = 0.f; acc1[m][r] = 0.f; }
#pragma unroll
    for (int s = 0; s < 4; ++s) {
#pragma unroll
        for (int m = 0; m < 4; ++m) {
            short8 afr = *(const short8*)&At[(m * 16 + lm) * STC + s * 32 + quad * 8];
            acc0[m] = __builtin_amdgcn_mfma_f32_16x16x32_bf16(afr, b0s[s], acc0[m], 0, 0, 0);
            acc1[m] = __builtin_amdgcn_mfma_f32_16x16x32_bf16(afr, b1s[s], acc1[m], 0, 0, 0);
        }
    }
    // add-back: one uint per (m,r) holds both acc0 (lo) and acc1 (hi) columns
    {
        const unsigned int* Spq32 = (const unsigned int*)SpqB;
        for (int m = 0; m < 4; ++m)
            for (int r = 0; r < 4; ++r) {
                int rw = m * 16 + quad * 4 + r;
                unsigned int pq = Spq32[rw * (SPQ / 2) + 16 * w + lm];
                acc0[m][r] = fmaxf(acc0[m][r] + bflo(pq), 0.f);
                acc1[m][r] = fmaxf(acc1[m][r] + bfhi(pq), 0.f);
            }
    }
    __syncthreads();
    {
        unsigned int* z1u = (unsigned int*)z1;
        for (int m = 0; m < 4; ++m)
            for (int r = 0; r < 4; ++r) {
                int rw = m * 16 + quad * 4 + r;
                z1u[rw * (STC / 2) + 16 * w + lm] = cvtpk(acc0[m][r], acc1[m][r]);
            }
    }
    __syncthreads();

    {
        f32x4 acc2[4];
        for (int m = 0; m < 4; ++m)
            for (int r = 0; r < 4; ++r) acc2[m][r] = bv2;
#pragma unroll
        for (int s = 0; s < 4; ++s) {
#pragma unroll
            for (int m = 0; m < 4; ++m) {
                short8 afr = *(const short8*)&z1[(m * 16 + lm) * STC + s * 32 + quad * 8];
                acc2[m] = __builtin_amdgcn_mfma_f32_16x16x32_bf16(afr, b2s[s], acc2[m], 0, 0, 0);
            }
        }
        for (int m = 0; m < 4; ++m)
            for (int r = 0; r < 4; ++r)
                z2[(m * 16 + quad * 4 + r) * Z2S + w * 16 + lm] = fmaxf(acc2[m][r], 0.f);
    }
    __syncthreads();

    {
        int e = tid & 63, q = tid >> 6;
        int c = q & 1, hf = q >> 1;
        const float* zr = z2 + e * Z2S + hf * 32;
        const float* wc = Wc3 + hf * 64 + c;
        float acc = 0.f;
#pragma unroll 8
        for (int kk = 0; kk < 32; ++kk)
            acc = fmaf(zr[kk], wc[2 * kk], acc);
        part[q * 64 + e] = acc;
    }
    __syncthreads();
    if (tid < 64) {
        int p = e0 + tid;
        if (p < E) {
            float l0 = bc3[0] + part[tid] + part[128 + tid];
            float l1 = bc3[1] + part[64 + tid] + part[192 + tid];
            float m = fmaxf(l0, l1);
            float lse = m + logf(expf(l0 - m) + expf(l1 - m));
            ((float2*)out)[eS[tid]] = make_float2(l0 - lse, l1 - lse);
        }
    }
}

// ---------------- launch ----------------

extern "C" void kernel_launch(void* const* d_in, const int* in_sizes, int n_in,
                              void* d_out, int out_size, void* d_ws, size_t ws_size,
                              hipStream_t stream) {
    const float* x   = (const float*)d_in[0];
    const int*   ei  = (const int*)d_in[1];
    const float* ea  = (const float*)d_in[2];
    const float* W1  = (const float*)d_in[3];
    const float* b1  = (const float*)d_in[4];
    const float* W2  = (const float*)d_in[5];
    const float* b2  = (const float*)d_in[6];
    const float* W3  = (const float*)d_in[7];
    const float* b3  = (const float*)d_in[8];
    const float* We1 = (const float*)d_in[9];
    const float* be1 = (const float*)d_in[10];
    const float* We2 = (const float*)d_in[11];
    const float* be2 = (const float*)d_in[12];
    const float* Wc1 = (const float*)d_in[13];
    const float* bc1 = (const float*)d_in[14];
    const float* Wc2 = (const float*)d_in[15];
    const float* bc2 = (const float*)d_in[16];
    const float* Wc3 = (const float*)d_in[17];
    const float* bc3 = (const float*)d_in[18];
    float* out = (float*)d_out;

    int N = in_sizes[0] / 8;
    int E = in_sizes[1] / 2;
    const int* row = ei;
    const int* col = ei + E;
    int NB = (N + 1023) / 1024;
    int ntiles = (E + 63) / 64;

    char* w = (char*)d_ws;
    auto alloc = [&](size_t bytes) { void* p = (void*)w; w += (bytes + 255) & ~(size_t)255; return p; };
    int*   cnt       = (int*)alloc((size_t)N * 4);
    int*   col_start = (int*)alloc((size_t)(N + 1) * 4);
    int*   cursor    = (int*)alloc((size_t)N * 4);
    int*   csc_src   = (int*)alloc((size_t)E * 4);
    int2*  csc_ec    = (int2*)alloc((size_t)E * 8);
    float* dinv      = (float*)alloc((size_t)N * 4);
    int*   bsum      = (int*)alloc(64 * 4);
    int*   boff      = (int*)alloc(64 * 4);
    float* Weff      = (float*)alloc(128 * 128 * 4);
    float* bc1p      = (float*)alloc(128 * 4);
    unsigned short* BpA  = (unsigned short*)alloc(32768);
    unsigned short* BpB  = (unsigned short*)alloc(32768);
    unsigned short* BpU  = (unsigned short*)alloc(32768);
    unsigned short* BpW2 = (unsigned short*)alloc(32768);
    unsigned short* BpW3 = (unsigned short*)alloc(32768);
    unsigned short* Bp2  = (unsigned short*)alloc(16384);
    unsigned short* BpE  = (unsigned short*)alloc(8192);
    float* xs   = (float*)alloc((size_t)N * 8 * 4);
    unsigned short* bufA = (unsigned short*)alloc((size_t)N * H * 2);
    unsigned short* bufB = (unsigned short*)alloc((size_t)N * H * 2);
    unsigned short* Pm   = (unsigned short*)alloc((size_t)N * H * 2);
    unsigned short* Qm   = (unsigned short*)alloc((size_t)N * H * 2);

    // graph build (CSC with eid+col); scan_write also emits dinv-prescaled xs
    hipMemsetAsync(cnt, 0, (size_t)N * 4, stream);
    count_kernel<<<(E + 255) / 256, 256, 0, stream>>>(col, E, cnt);
    scan_sum_kernel<<<NB, 256, 0, stream>>>(cnt, N, bsum);
    scan_offsets_kernel<<<1, 64, 0, stream>>>(bsum, NB, boff, col_start, N);
    scan_write_kernel<<<NB, 256, 0, stream>>>(cnt, N, boff, col_start, cursor, dinv, x, xs);
    scatter_kernel<<<(E + 255) / 256, 256, 0, stream>>>(row, col, E, cursor, csc_src, csc_ec);

    // weight prep: weff, then all packs + bc1p in ONE launch
    weff_kernel<<<64, 256, 0, stream>>>(We2, Wc1, Weff);
    prep_pack_kernel<<<47, 256, 0, stream>>>(Wc1, Weff, W2, W3, Wc2, We1, be1, bc1, be2,
                                             BpA, BpB, BpU, BpW2, BpW3, Bp2, BpE, bc1p);

    // GCN: fused layer-1 (agg + 8->128 xform), then bf16 agg/xform chain
    agg1x_kernel<<<(N + 3) / 4, 256, 0, stream>>>(xs, col_start, csc_src, dinv, W1, b1,
                                                  (unsigned int*)bufA, N);               // h1d
    agg128bf_kernel<<<(N + 3) / 4, 256, 0, stream>>>((const unsigned int*)bufA, col_start, csc_src,
                                                     dinv, (unsigned int*)bufB, N);      // agg2
    xform_mfma_kernel<<<(N + 63) / 64, 256, 0, stream>>>(bufB, BpW2, b2, dinv, bufA, N); // h2d
    agg128bf_kernel<<<(N + 3) / 4, 256, 0, stream>>>((const unsigned int*)bufA, col_start, csc_src,
                                                     dinv, (unsigned int*)bufB, N);      // agg3
    h3pq_kernel<<<(N + 63) / 64, 256, 0, stream>>>(bufB, BpW3, b3, BpA, BpB, bc1p, Pm, Qm, N);

    // fused all-MFMA classifier in CSC order (1 tile/block)
    classifier_mfma2<<<ntiles, 256, 0, stream>>>(
        csc_src, csc_ec, ea, BpE, Pm, Qm, BpU, Bp2, bc2, Wc3, bc3, out, E);
}